// Round 6
// baseline (1110.919 us; speedup 1.0000x reference)
//
#include <hip/hip_runtime.h>
#include <stdint.h>

#define HEADS 12
#define HD 64
#define NB 16
#define NTOK 577
#define NP 592                 // padded token count for Vt rows (16B-aligned)
#define CDIM 768
#define MROWS (NB * NTOK)      // 9232
#define NBH (NB * HEADS)       // 192
#define ATT_SCALE 0.125f       // 64^-0.5
#define LOG2E 1.4426950408889634f
#define CLS_CONST 9999.0f

typedef short s16x8 __attribute__((ext_vector_type(8)));
typedef __bf16 bf16x8 __attribute__((ext_vector_type(8)));
typedef __bf16 bf16x4 __attribute__((ext_vector_type(4)));
typedef float f32x4 __attribute__((ext_vector_type(4)));

__device__ inline bf16x8 as_bf16(s16x8 v) { union { s16x8 s; bf16x8 b; } u; u.s = v; return u.b; }
__device__ inline float bf2f(unsigned short u) { union { unsigned int i; float f; } v; v.i = ((unsigned int)u) << 16; return v.f; }
__device__ inline unsigned short f2bf(float f) {
  union { float f; unsigned int i; } v; v.f = f;
  return (unsigned short)((v.i + 0x7FFFu + ((v.i >> 16) & 1u)) >> 16);
}
// f32x4 -> bf16x4 convert + 8B LDS store (compiler emits v_cvt_pk_bf16_f32)
__device__ inline void cvt_store8(unsigned char* dst, f32x4 v) {
  bf16x4 b;
  b[0] = (__bf16)v[0]; b[1] = (__bf16)v[1]; b[2] = (__bf16)v[2]; b[3] = (__bf16)v[3];
  *reinterpret_cast<bf16x4*>(dst) = b;
}

// Stage one 128x64 operand tile (f32 or bf16 source) into swizzled bf16 LDS.
template<typename T>
__device__ inline void stage_tile(unsigned char* dst, const T* src, int row0, int rowMax,
                                  int K, int k0, int tid) {
  if constexpr (sizeof(T) == 4) {
    #pragma unroll
    for (int i = 0; i < 8; ++i) {
      int c = tid + i * 256;
      int row = c >> 4, col4 = c & 15;
      int off = (row * 128 + col4 * 8) ^ ((row & 7) << 4);
      f32x4 v = {};
      if (row0 + row < rowMax)
        v = *reinterpret_cast<const f32x4*>((const float*)src + (size_t)(row0 + row) * K + k0 + col4 * 4);
      cvt_store8(dst + off, v);
    }
  } else {
    #pragma unroll
    for (int i = 0; i < 4; ++i) {
      int c = tid + i * 256;
      int row = c >> 3, col = c & 7;
      int off = (row * 128 + col * 16) ^ ((row & 7) << 4);
      s16x8 v = {};
      if (row0 + row < rowMax)
        v = *reinterpret_cast<const s16x8*>((const unsigned short*)src + (size_t)(row0 + row) * K + k0 + col * 8);
      *reinterpret_cast<s16x8*>(dst + off) = v;
    }
  }
}

// ---------------- GEMM (NT): C[M,N] = A[M,K] @ B[N,K]^T, MFMA bf16 ----------------
// MODE 0: A=f32 x, B=f32 qkv_w; scatter epilogue to Q/K/Vt (bf16 scratch).
// MODE 1: A=bf16 AO, B=f32 proj_w; +bias epilogue -> Out (FLOAT32, the real output).
template<int MODE, typename ATy, typename BTy>
__global__ __launch_bounds__(256) void gemm_nt(
    const ATy* __restrict__ A, const BTy* __restrict__ Bw,
    int M, int K,
    unsigned short* __restrict__ Qo, unsigned short* __restrict__ Ko,
    unsigned short* __restrict__ Vt,
    float* __restrict__ Out, const float* __restrict__ bias)
{
  __shared__ __align__(16) unsigned char As[128 * 128];
  __shared__ __align__(16) unsigned char Bs[128 * 128];
  const int m0 = blockIdx.x * 128, n0 = blockIdx.y * 128;
  const int tid = threadIdx.x;
  const int lane = tid & 63, w = tid >> 6;
  const int r = lane & 15, g = lane >> 4;
  const int wr = (w >> 1) * 64, wc = (w & 1) * 64;
  f32x4 acc[4][4] = {};

  for (int k0 = 0; k0 < K; k0 += 64) {
    stage_tile(As, A,  m0, M,       K, k0, tid);
    stage_tile(Bs, Bw, n0, 1 << 30, K, k0, tid);   // B rows are always full tiles here
    __syncthreads();

    s16x8 af[4][2], bf[4][2];
    #pragma unroll
    for (int mi = 0; mi < 4; ++mi) {
      int row = wr + mi * 16 + r;
      #pragma unroll
      for (int ks = 0; ks < 2; ++ks)
        af[mi][ks] = *reinterpret_cast<const s16x8*>(
            As + ((row * 128 + ks * 64 + g * 16) ^ ((row & 7) << 4)));
    }
    #pragma unroll
    for (int ni = 0; ni < 4; ++ni) {
      int row = wc + ni * 16 + r;
      #pragma unroll
      for (int ks = 0; ks < 2; ++ks)
        bf[ni][ks] = *reinterpret_cast<const s16x8*>(
            Bs + ((row * 128 + ks * 64 + g * 16) ^ ((row & 7) << 4)));
    }
    #pragma unroll
    for (int mi = 0; mi < 4; ++mi)
      #pragma unroll
      for (int ni = 0; ni < 4; ++ni) {
        acc[mi][ni] = __builtin_amdgcn_mfma_f32_16x16x32_bf16(
            as_bf16(af[mi][0]), as_bf16(bf[ni][0]), acc[mi][ni], 0, 0, 0);
        acc[mi][ni] = __builtin_amdgcn_mfma_f32_16x16x32_bf16(
            as_bf16(af[mi][1]), as_bf16(bf[ni][1]), acc[mi][ni], 0, 0, 0);
      }
    __syncthreads();
  }

  // ---- epilogue.  C/D layout: col = lane&15 (r), row = (lane>>4)*4 + reg ----
  #pragma unroll
  for (int mi = 0; mi < 4; ++mi) {
    #pragma unroll
    for (int ni = 0; ni < 4; ++ni) {
      int gc = n0 + wc + ni * 16 + r;
      #pragma unroll
      for (int i = 0; i < 4; ++i) {
        int gr = m0 + wr + mi * 16 + g * 4 + i;
        if (gr >= M) continue;
        float val = acc[mi][ni][i];
        if (MODE == 0) {
          int b = gr / NTOK, n = gr - b * NTOK;
          int which = gc / CDIM, rem = gc - which * CDIM;
          int h = rem >> 6, d = rem & 63;
          int bh = b * HEADS + h;
          unsigned short bv = f2bf(val);
          if (which == 0)      Qo[((size_t)bh * NTOK + n) * HD + d] = bv;
          else if (which == 1) Ko[((size_t)bh * NTOK + n) * HD + d] = bv;
          else                 Vt[((size_t)bh * HD + d) * NP + n] = bv;
        } else {
          Out[(size_t)gr * CDIM + gc] = val + bias[gc];   // f32 store
        }
      }
    }
  }
}

// ---------------- Flash attention: per (b,h), 64 q-rows per block (4 waves x 16) --------
// Q,K,Vt bf16 scratch; AO written bf16 (feeds proj GEMM's bf16 A path).
__global__ __launch_bounds__(256) void attn_kernel(
    const unsigned short* __restrict__ Q, const unsigned short* __restrict__ Kd,
    const unsigned short* __restrict__ Vt, unsigned short* __restrict__ AO)
{
  __shared__ __align__(16) unsigned char Pl[4][2048];
  const int qt = blockIdx.x;
  const int bh = blockIdx.y;
  const int tid = threadIdx.x;
  const int w = tid >> 6, lane = tid & 63;
  const int r = lane & 15, g = lane >> 4;
  const int q0 = qt * 64 + w * 16;
  const unsigned short* Qb = Q + (size_t)bh * NTOK * HD;
  const unsigned short* Kb = Kd + (size_t)bh * NTOK * HD;
  const unsigned short* Vb = Vt + (size_t)bh * HD * NP;
  unsigned char* P = Pl[w];

  int qr = q0 + r; if (qr > NTOK - 1) qr = NTOK - 1;
  s16x8 aq0 = *reinterpret_cast<const s16x8*>(Qb + (size_t)qr * HD + g * 8);
  s16x8 aq1 = *reinterpret_cast<const s16x8*>(Qb + (size_t)qr * HD + 32 + g * 8);

  f32x4 O[4] = {};
  float m2[4], l[4];
  #pragma unroll
  for (int i = 0; i < 4; ++i) { m2[i] = -3.0e38f; l[i] = 0.f; }
  const float sl = ATT_SCALE * LOG2E;

  for (int kt = 0; kt < 10; ++kt) {
    const int kb = kt * 64;
    f32x4 s[4] = {};
    #pragma unroll
    for (int f = 0; f < 4; ++f) {
      int kk = kb + f * 16 + r; if (kk > NTOK - 1) kk = NTOK - 1;
      s16x8 b0 = *reinterpret_cast<const s16x8*>(Kb + (size_t)kk * HD + g * 8);
      s16x8 b1 = *reinterpret_cast<const s16x8*>(Kb + (size_t)kk * HD + 32 + g * 8);
      s[f] = __builtin_amdgcn_mfma_f32_16x16x32_bf16(as_bf16(aq0), as_bf16(b0), s[f], 0, 0, 0);
      s[f] = __builtin_amdgcn_mfma_f32_16x16x32_bf16(as_bf16(aq1), as_bf16(b1), s[f], 0, 0, 0);
    }
    float rmax[4];
    #pragma unroll
    for (int i = 0; i < 4; ++i) rmax[i] = -3.0e38f;
    #pragma unroll
    for (int f = 0; f < 4; ++f) {
      const bool valid = (kb + f * 16 + r) < NTOK;
      #pragma unroll
      for (int i = 0; i < 4; ++i) {
        float v = valid ? s[f][i] * sl : -3.0e38f;
        s[f][i] = v;
        rmax[i] = fmaxf(rmax[i], v);
      }
    }
    #pragma unroll
    for (int off = 1; off < 16; off <<= 1)
      #pragma unroll
      for (int i = 0; i < 4; ++i) rmax[i] = fmaxf(rmax[i], __shfl_xor(rmax[i], off, 64));

    float alpha[4], rs[4];
    #pragma unroll
    for (int i = 0; i < 4; ++i) {
      float mn = fmaxf(m2[i], rmax[i]);
      alpha[i] = exp2f(fminf(m2[i] - mn, 0.f));
      m2[i] = mn;
      rs[i] = 0.f;
    }
    #pragma unroll
    for (int f = 0; f < 4; ++f) {
      #pragma unroll
      for (int i = 0; i < 4; ++i) {
        float p = exp2f(fminf(s[f][i] - m2[i], 0.f));
        rs[i] += p;
        int prow = g * 4 + i;
        int boff = (prow * 128 + (f * 16 + r) * 2) ^ ((prow & 7) << 4);
        *reinterpret_cast<unsigned short*>(P + boff) = f2bf(p);
      }
    }
    #pragma unroll
    for (int off = 1; off < 16; off <<= 1)
      #pragma unroll
      for (int i = 0; i < 4; ++i) rs[i] += __shfl_xor(rs[i], off, 64);
    #pragma unroll
    for (int i = 0; i < 4; ++i) l[i] = l[i] * alpha[i] + rs[i];
    #pragma unroll
    for (int f = 0; f < 4; ++f)
      #pragma unroll
      for (int i = 0; i < 4; ++i) O[f][i] *= alpha[i];

    #pragma unroll
    for (int ks = 0; ks < 2; ++ks) {
      s16x8 pa = *reinterpret_cast<const s16x8*>(
          P + ((r * 128 + ks * 64 + g * 16) ^ ((r & 7) << 4)));
      int nn = kb + ks * 32 + g * 8; if (nn >= NTOK) nn = 0;   // masked keys have p=0
      #pragma unroll
      for (int f = 0; f < 4; ++f) {
        s16x8 bv = *reinterpret_cast<const s16x8*>(Vb + (size_t)(f * 16 + r) * NP + nn);
        O[f] = __builtin_amdgcn_mfma_f32_16x16x32_bf16(as_bf16(pa), as_bf16(bv), O[f], 0, 0, 0);
      }
    }
  }

  const int b = bh / HEADS, h = bh - b * HEADS;
  float inv[4];
  #pragma unroll
  for (int i = 0; i < 4; ++i) inv[i] = 1.0f / fmaxf(l[i], 1e-20f);
  #pragma unroll
  for (int f = 0; f < 4; ++f)
    #pragma unroll
    for (int i = 0; i < 4; ++i) {
      int row = q0 + g * 4 + i;
      if (row < NTOK)
        AO[((size_t)(b * NTOK + row)) * CDIM + h * HD + f * 16 + r] = f2bf(O[f][i] * inv[i]);
    }
}

// ---------------- CLS-row scores -> f32 output chunk 1 ----------------
__global__ __launch_bounds__(256) void scores_kernel(
    const unsigned short* __restrict__ Q, const unsigned short* __restrict__ Kd,
    const unsigned short* __restrict__ Vt, float* __restrict__ Sc)
{
  __shared__ float qv[64];
  __shared__ float sig[NTOK];
  __shared__ float red[256];
  const int b = blockIdx.x, tid = threadIdx.x;
  for (int k = tid; k < NTOK; k += 256) sig[k] = 0.f;
  __syncthreads();
  const float sl = ATT_SCALE * LOG2E;

  for (int h = 0; h < HEADS; ++h) {
    const int bh = b * HEADS + h;
    if (tid < 64) qv[tid] = bf2f(Q[((size_t)bh * NTOK) * HD + tid]);
    __syncthreads();
    float sv[3];
    #pragma unroll
    for (int j = 0; j < 3; ++j) {
      int k = tid + j * 256;
      float s = -3.0e38f;
      if (k < NTOK) {
        const unsigned short* kr = Kd + ((size_t)bh * NTOK + k) * HD;
        float acc = 0.f;
        #pragma unroll
        for (int d = 0; d < 64; ++d) acc += qv[d] * bf2f(kr[d]);
        s = acc * sl;
      }
      sv[j] = s;
    }
    float lm = fmaxf(fmaxf(sv[0], sv[1]), sv[2]);
    red[tid] = lm; __syncthreads();
    for (int st = 128; st > 0; st >>= 1) {
      if (tid < st) red[tid] = fmaxf(red[tid], red[tid + st]);
      __syncthreads();
    }
    float mx = red[0]; __syncthreads();
    float pv[3]; float ps = 0.f;
    #pragma unroll
    for (int j = 0; j < 3; ++j) { pv[j] = exp2f(fminf(sv[j] - mx, 0.f)); ps += pv[j]; }
    red[tid] = ps; __syncthreads();
    for (int st = 128; st > 0; st >>= 1) {
      if (tid < st) red[tid] += red[tid + st];
      __syncthreads();
    }
    float itot = 1.f / fmaxf(red[0], 1e-20f); __syncthreads();
    #pragma unroll
    for (int j = 0; j < 3; ++j) {
      int k = tid + j * 256;
      if (k < NTOK) sig[k] += pv[j] * itot;
    }
    __syncthreads();
  }

  float vacc[3] = {0.f, 0.f, 0.f};
  for (int hd = 0; hd < CDIM; ++hd) {
    const unsigned short* vr = Vt + ((size_t)b * CDIM + hd) * NP;
    #pragma unroll
    for (int j = 0; j < 3; ++j) {
      int k = tid + j * 256;
      if (k < NTOK) { float v = bf2f(vr[k]); vacc[j] += v * v; }
    }
  }
  float wv[3]; float part = 0.f;
  #pragma unroll
  for (int j = 0; j < 3; ++j) {
    int k = tid + j * 256;
    wv[j] = 0.f;
    if (k < NTOK) {
      wv[j] = sig[k] * sqrtf(vacc[j]);
      if (k >= 1) part += wv[j];
    }
  }
  red[tid] = part; __syncthreads();
  for (int st = 128; st > 0; st >>= 1) {
    if (tid < st) red[tid] += red[tid + st];
    __syncthreads();
  }
  const float itot = 1.f / fmaxf(red[0], 1e-20f);
  #pragma unroll
  for (int j = 0; j < 3; ++j) {
    int k = tid + j * 256;
    if (k == 0)           Sc[(size_t)b * NTOK] = CLS_CONST;          // f32 store
    else if (k < NTOK)    Sc[(size_t)b * NTOK + k] = wv[j] * itot;   // f32 store
  }
}

extern "C" void kernel_launch(void* const* d_in, const int* in_sizes, int n_in,
                              void* d_out, int out_size, void* d_ws, size_t ws_size,
                              hipStream_t stream) {
  (void)in_sizes; (void)n_in; (void)out_size; (void)ws_size;
  const float* x      = (const float*)d_in[0];   // f32 inputs
  const float* qkv_w  = (const float*)d_in[1];
  const float* proj_w = (const float*)d_in[2];
  const float* proj_b = (const float*)d_in[3];
  float* out    = (float*)d_out;                 // f32 outputs (reference dtype)
  float* scores = out + (size_t)MROWS * CDIM;

  // All scratch in d_ws only (57.1 MB bf16). No input/output aliasing.
  const size_t qN  = (size_t)NBH * NTOK * HD;
  const size_t vtN = (size_t)NBH * HD * NP;
  unsigned short* Q  = (unsigned short*)d_ws;
  unsigned short* K  = Q + qN;
  unsigned short* Vt = K + qN;
  unsigned short* AO = Vt + vtN;

  gemm_nt<0, float, float><<<dim3(73, 18), 256, 0, stream>>>(
      x, qkv_w, MROWS, CDIM, Q, K, Vt, nullptr, nullptr);
  attn_kernel<<<dim3(10, NBH), 256, 0, stream>>>(Q, K, Vt, AO);
  gemm_nt<1, unsigned short, float><<<dim3(73, 6), 256, 0, stream>>>(
      AO, proj_w, MROWS, CDIM, nullptr, nullptr, nullptr, out, proj_b);
  scores_kernel<<<dim3(NB), 256, 0, stream>>>(Q, K, Vt, scores);
}

// Round 7
// 530.244 us; speedup vs baseline: 2.0951x; 2.0951x over previous
//
#include <hip/hip_runtime.h>
#include <stdint.h>

#define HEADS 12
#define HD 64
#define NB 16
#define NTOK 577
#define NP 592                 // padded token count for Vt rows (16B-aligned)
#define CDIM 768
#define MROWS (NB * NTOK)      // 9232
#define NBH (NB * HEADS)       // 192
#define ATT_SCALE 0.125f       // 64^-0.5
#define LOG2E 1.4426950408889634f
#define CLS_CONST 9999.0f

typedef short s16x8 __attribute__((ext_vector_type(8)));
typedef __bf16 bf16x8 __attribute__((ext_vector_type(8)));
typedef __bf16 bf16x4 __attribute__((ext_vector_type(4)));
typedef float f32x4 __attribute__((ext_vector_type(4)));

__device__ inline bf16x8 as_bf16(s16x8 v) { union { s16x8 s; bf16x8 b; } u; u.s = v; return u.b; }
__device__ inline float bf2f(unsigned short u) { union { unsigned int i; float f; } v; v.i = ((unsigned int)u) << 16; return v.f; }
__device__ inline unsigned short f2bf(float f) {
  union { float f; unsigned int i; } v; v.f = f;
  return (unsigned short)((v.i + 0x7FFFu + ((v.i >> 16) & 1u)) >> 16);
}
// f32x4 -> bf16x4 convert + 8B LDS store (compiler emits v_cvt_pk_bf16_f32)
__device__ inline void cvt_store8(unsigned char* dst, f32x4 v) {
  bf16x4 b;
  b[0] = (__bf16)v[0]; b[1] = (__bf16)v[1]; b[2] = (__bf16)v[2]; b[3] = (__bf16)v[3];
  *reinterpret_cast<bf16x4*>(dst) = b;
}

// Stage one 128x64 operand tile (f32 or bf16 source) into swizzled bf16 LDS.
template<typename T>
__device__ inline void stage_tile(unsigned char* dst, const T* src, int row0, int rowMax,
                                  int K, int k0, int tid) {
  if constexpr (sizeof(T) == 4) {
    #pragma unroll
    for (int i = 0; i < 8; ++i) {
      int c = tid + i * 256;
      int row = c >> 4, col4 = c & 15;
      int off = (row * 128 + col4 * 8) ^ ((row & 7) << 4);
      f32x4 v = {};
      if (row0 + row < rowMax)
        v = *reinterpret_cast<const f32x4*>((const float*)src + (size_t)(row0 + row) * K + k0 + col4 * 4);
      cvt_store8(dst + off, v);
    }
  } else {
    #pragma unroll
    for (int i = 0; i < 4; ++i) {
      int c = tid + i * 256;
      int row = c >> 3, col = c & 7;
      int off = (row * 128 + col * 16) ^ ((row & 7) << 4);
      s16x8 v = {};
      if (row0 + row < rowMax)
        v = *reinterpret_cast<const s16x8*>((const unsigned short*)src + (size_t)(row0 + row) * K + k0 + col * 8);
      *reinterpret_cast<s16x8*>(dst + off) = v;
    }
  }
}

// ---------------- GEMM (NT): C[M,N] = A[M,K] @ B[N,K]^T, MFMA bf16 ----------------
// MODE 0: A=f32 x, B=f32 qkv_w; scatter epilogue to Q/K/Vt (bf16 scratch).
// MODE 1: A=bf16 AO, B=f32 proj_w; +bias epilogue -> Out (f32 output).
template<int MODE, typename ATy, typename BTy>
__global__ __launch_bounds__(256) void gemm_nt(
    const ATy* __restrict__ A, const BTy* __restrict__ Bw,
    int M, int K,
    unsigned short* __restrict__ Qo, unsigned short* __restrict__ Ko,
    unsigned short* __restrict__ Vt,
    float* __restrict__ Out, const float* __restrict__ bias)
{
  __shared__ __align__(16) unsigned char As[128 * 128];
  __shared__ __align__(16) unsigned char Bs[128 * 128];
  const int m0 = blockIdx.x * 128, n0 = blockIdx.y * 128;
  const int tid = threadIdx.x;
  const int lane = tid & 63, w = tid >> 6;
  const int r = lane & 15, g = lane >> 4;
  const int wr = (w >> 1) * 64, wc = (w & 1) * 64;
  f32x4 acc[4][4] = {};

  for (int k0 = 0; k0 < K; k0 += 64) {
    stage_tile(As, A,  m0, M,       K, k0, tid);
    stage_tile(Bs, Bw, n0, 1 << 30, K, k0, tid);   // B rows are always full tiles here
    __syncthreads();

    s16x8 af[4][2], bf[4][2];
    #pragma unroll
    for (int mi = 0; mi < 4; ++mi) {
      int row = wr + mi * 16 + r;
      #pragma unroll
      for (int ks = 0; ks < 2; ++ks)
        af[mi][ks] = *reinterpret_cast<const s16x8*>(
            As + ((row * 128 + ks * 64 + g * 16) ^ ((row & 7) << 4)));
    }
    #pragma unroll
    for (int ni = 0; ni < 4; ++ni) {
      int row = wc + ni * 16 + r;
      #pragma unroll
      for (int ks = 0; ks < 2; ++ks)
        bf[ni][ks] = *reinterpret_cast<const s16x8*>(
            Bs + ((row * 128 + ks * 64 + g * 16) ^ ((row & 7) << 4)));
    }
    #pragma unroll
    for (int mi = 0; mi < 4; ++mi)
      #pragma unroll
      for (int ni = 0; ni < 4; ++ni) {
        acc[mi][ni] = __builtin_amdgcn_mfma_f32_16x16x32_bf16(
            as_bf16(af[mi][0]), as_bf16(bf[ni][0]), acc[mi][ni], 0, 0, 0);
        acc[mi][ni] = __builtin_amdgcn_mfma_f32_16x16x32_bf16(
            as_bf16(af[mi][1]), as_bf16(bf[ni][1]), acc[mi][ni], 0, 0, 0);
      }
    __syncthreads();
  }

  // ---- epilogue.  C/D layout: col = lane&15 (r), row = (lane>>4)*4 + reg ----
  #pragma unroll
  for (int mi = 0; mi < 4; ++mi) {
    #pragma unroll
    for (int ni = 0; ni < 4; ++ni) {
      int gc = n0 + wc + ni * 16 + r;
      #pragma unroll
      for (int i = 0; i < 4; ++i) {
        int gr = m0 + wr + mi * 16 + g * 4 + i;
        if (gr >= M) continue;
        float val = acc[mi][ni][i];
        if (MODE == 0) {
          int b = gr / NTOK, n = gr - b * NTOK;
          int which = gc / CDIM, rem = gc - which * CDIM;
          int h = rem >> 6, d = rem & 63;
          int bh = b * HEADS + h;
          unsigned short bv = f2bf(val);
          if (which == 0)      Qo[((size_t)bh * NTOK + n) * HD + d] = bv;
          else if (which == 1) Ko[((size_t)bh * NTOK + n) * HD + d] = bv;
          else                 Vt[((size_t)bh * HD + d) * NP + n] = bv;
        } else {
          Out[(size_t)gr * CDIM + gc] = val + bias[gc];   // f32 store
        }
      }
    }
  }
}

// ---------------- Flash attention: per (b,h), 64 q-rows per block (4 waves x 16) --------
__global__ __launch_bounds__(256) void attn_kernel(
    const unsigned short* __restrict__ Q, const unsigned short* __restrict__ Kd,
    const unsigned short* __restrict__ Vt, unsigned short* __restrict__ AO)
{
  __shared__ __align__(16) unsigned char Pl[4][2048];
  const int qt = blockIdx.x;
  const int bh = blockIdx.y;
  const int tid = threadIdx.x;
  const int w = tid >> 6, lane = tid & 63;
  const int r = lane & 15, g = lane >> 4;
  const int q0 = qt * 64 + w * 16;
  const unsigned short* Qb = Q + (size_t)bh * NTOK * HD;
  const unsigned short* Kb = Kd + (size_t)bh * NTOK * HD;
  const unsigned short* Vb = Vt + (size_t)bh * HD * NP;
  unsigned char* P = Pl[w];

  int qr = q0 + r; if (qr > NTOK - 1) qr = NTOK - 1;
  s16x8 aq0 = *reinterpret_cast<const s16x8*>(Qb + (size_t)qr * HD + g * 8);
  s16x8 aq1 = *reinterpret_cast<const s16x8*>(Qb + (size_t)qr * HD + 32 + g * 8);

  f32x4 O[4] = {};
  float m2[4], l[4];
  #pragma unroll
  for (int i = 0; i < 4; ++i) { m2[i] = -3.0e38f; l[i] = 0.f; }
  const float sl = ATT_SCALE * LOG2E;

  for (int kt = 0; kt < 10; ++kt) {
    const int kb = kt * 64;
    f32x4 s[4] = {};
    #pragma unroll
    for (int f = 0; f < 4; ++f) {
      int kk = kb + f * 16 + r; if (kk > NTOK - 1) kk = NTOK - 1;
      s16x8 b0 = *reinterpret_cast<const s16x8*>(Kb + (size_t)kk * HD + g * 8);
      s16x8 b1 = *reinterpret_cast<const s16x8*>(Kb + (size_t)kk * HD + 32 + g * 8);
      s[f] = __builtin_amdgcn_mfma_f32_16x16x32_bf16(as_bf16(aq0), as_bf16(b0), s[f], 0, 0, 0);
      s[f] = __builtin_amdgcn_mfma_f32_16x16x32_bf16(as_bf16(aq1), as_bf16(b1), s[f], 0, 0, 0);
    }
    float rmax[4];
    #pragma unroll
    for (int i = 0; i < 4; ++i) rmax[i] = -3.0e38f;
    #pragma unroll
    for (int f = 0; f < 4; ++f) {
      const bool valid = (kb + f * 16 + r) < NTOK;
      #pragma unroll
      for (int i = 0; i < 4; ++i) {
        float v = valid ? s[f][i] * sl : -3.0e38f;
        s[f][i] = v;
        rmax[i] = fmaxf(rmax[i], v);
      }
    }
    #pragma unroll
    for (int off = 1; off < 16; off <<= 1)
      #pragma unroll
      for (int i = 0; i < 4; ++i) rmax[i] = fmaxf(rmax[i], __shfl_xor(rmax[i], off, 64));

    float alpha[4], rs[4];
    #pragma unroll
    for (int i = 0; i < 4; ++i) {
      float mn = fmaxf(m2[i], rmax[i]);
      alpha[i] = exp2f(fminf(m2[i] - mn, 0.f));
      m2[i] = mn;
      rs[i] = 0.f;
    }
    #pragma unroll
    for (int f = 0; f < 4; ++f) {
      #pragma unroll
      for (int i = 0; i < 4; ++i) {
        float p = exp2f(fminf(s[f][i] - m2[i], 0.f));
        rs[i] += p;
        int prow = g * 4 + i;
        int boff = (prow * 128 + (f * 16 + r) * 2) ^ ((prow & 7) << 4);
        *reinterpret_cast<unsigned short*>(P + boff) = f2bf(p);
      }
    }
    #pragma unroll
    for (int off = 1; off < 16; off <<= 1)
      #pragma unroll
      for (int i = 0; i < 4; ++i) rs[i] += __shfl_xor(rs[i], off, 64);
    #pragma unroll
    for (int i = 0; i < 4; ++i) l[i] = l[i] * alpha[i] + rs[i];
    #pragma unroll
    for (int f = 0; f < 4; ++f)
      #pragma unroll
      for (int i = 0; i < 4; ++i) O[f][i] *= alpha[i];

    #pragma unroll
    for (int ks = 0; ks < 2; ++ks) {
      s16x8 pa = *reinterpret_cast<const s16x8*>(
          P + ((r * 128 + ks * 64 + g * 16) ^ ((r & 7) << 4)));
      int nn = kb + ks * 32 + g * 8; if (nn >= NTOK) nn = 0;   // masked keys have p=0
      #pragma unroll
      for (int f = 0; f < 4; ++f) {
        s16x8 bv = *reinterpret_cast<const s16x8*>(Vb + (size_t)(f * 16 + r) * NP + nn);
        O[f] = __builtin_amdgcn_mfma_f32_16x16x32_bf16(as_bf16(pa), as_bf16(bv), O[f], 0, 0, 0);
      }
    }
  }

  const int b = bh / HEADS, h = bh - b * HEADS;
  float inv[4];
  #pragma unroll
  for (int i = 0; i < 4; ++i) inv[i] = 1.0f / fmaxf(l[i], 1e-20f);
  #pragma unroll
  for (int f = 0; f < 4; ++f)
    #pragma unroll
    for (int i = 0; i < 4; ++i) {
      int row = q0 + g * 4 + i;
      if (row < NTOK)
        AO[((size_t)(b * NTOK + row)) * CDIM + h * HD + f * 16 + r] = f2bf(O[f][i] * inv[i]);
    }
}

// ---------------- Scores phase A: per (b,h) CLS-softmax + partial v-norm^2 ------------
// grid = 192 blocks (one per bh). Writes SigPart[bh][k], VnPart[bh][k] (f32, NP-padded).
__global__ __launch_bounds__(256) void scores_partial(
    const unsigned short* __restrict__ Q, const unsigned short* __restrict__ Kd,
    const unsigned short* __restrict__ Vt,
    float* __restrict__ SigPart, float* __restrict__ VnPart)
{
  const int bh = blockIdx.x;
  const int tid = threadIdx.x;
  __shared__ float qv[64];
  __shared__ float red[256];
  if (tid < 64) qv[tid] = bf2f(Q[(size_t)bh * NTOK * HD + tid]);
  __syncthreads();
  const float sl = ATT_SCALE * LOG2E;
  const unsigned short* Kb = Kd + (size_t)bh * NTOK * HD;
  const unsigned short* Vb = Vt + (size_t)bh * HD * NP;

  // s = q0 . K[k] for 3 keys per thread
  float sv[3];
  #pragma unroll
  for (int j = 0; j < 3; ++j) {
    int k = tid + j * 256;
    float s = -3.0e38f;
    if (k < NTOK) {
      const unsigned short* kr = Kb + (size_t)k * HD;
      float acc = 0.f;
      #pragma unroll
      for (int d8 = 0; d8 < 8; ++d8) {
        s16x8 kv = *reinterpret_cast<const s16x8*>(kr + d8 * 8);
        #pragma unroll
        for (int e = 0; e < 8; ++e) acc += qv[d8 * 8 + e] * bf2f((unsigned short)kv[e]);
      }
      s = acc * sl;
    }
    sv[j] = s;
  }
  // block softmax (max, then sum)
  float lm = fmaxf(fmaxf(sv[0], sv[1]), sv[2]);
  red[tid] = lm; __syncthreads();
  for (int st = 128; st > 0; st >>= 1) {
    if (tid < st) red[tid] = fmaxf(red[tid], red[tid + st]);
    __syncthreads();
  }
  float mx = red[0]; __syncthreads();
  float pv[3], ps = 0.f;
  #pragma unroll
  for (int j = 0; j < 3; ++j) { pv[j] = exp2f(fminf(sv[j] - mx, 0.f)); ps += pv[j]; }  // invalid k -> 0
  red[tid] = ps; __syncthreads();
  for (int st = 128; st > 0; st >>= 1) {
    if (tid < st) red[tid] += red[tid + st];
    __syncthreads();
  }
  const float itot = 1.f / fmaxf(red[0], 1e-20f);
  #pragma unroll
  for (int j = 0; j < 3; ++j) {
    int k = tid + j * 256;
    if (k < NTOK) SigPart[(size_t)bh * NP + k] = pv[j] * itot;
  }
  // partial v-norm^2: sum over this head's 64 dims; reads contiguous in k (coalesced)
  float vacc[3] = {0.f, 0.f, 0.f};
  for (int d = 0; d < HD; ++d) {
    const unsigned short* vr = Vb + (size_t)d * NP;
    #pragma unroll
    for (int j = 0; j < 3; ++j) {
      int k = tid + j * 256;
      if (k < NTOK) { float v = bf2f(vr[k]); vacc[j] += v * v; }
    }
  }
  #pragma unroll
  for (int j = 0; j < 3; ++j) {
    int k = tid + j * 256;
    if (k < NTOK) VnPart[(size_t)bh * NP + k] = vacc[j];
  }
}

// ---------------- Scores phase B: combine heads, normalize, write f32 ------------------
__global__ __launch_bounds__(256) void scores_final(
    const float* __restrict__ SigPart, const float* __restrict__ VnPart,
    float* __restrict__ Sc)
{
  const int b = blockIdx.x;
  const int tid = threadIdx.x;
  __shared__ float red[256];
  float wv[3]; float part = 0.f;
  #pragma unroll
  for (int j = 0; j < 3; ++j) {
    int k = tid + j * 256;
    wv[j] = 0.f;
    if (k < NTOK) {
      float sig = 0.f, vn = 0.f;
      #pragma unroll
      for (int h = 0; h < HEADS; ++h) {
        sig += SigPart[((size_t)(b * HEADS + h)) * NP + k];
        vn  += VnPart [((size_t)(b * HEADS + h)) * NP + k];
      }
      wv[j] = sig * sqrtf(vn);
      if (k >= 1) part += wv[j];
    }
  }
  red[tid] = part; __syncthreads();
  for (int st = 128; st > 0; st >>= 1) {
    if (tid < st) red[tid] += red[tid + st];
    __syncthreads();
  }
  const float itot = 1.f / fmaxf(red[0], 1e-20f);
  #pragma unroll
  for (int j = 0; j < 3; ++j) {
    int k = tid + j * 256;
    if (k == 0)         Sc[(size_t)b * NTOK] = CLS_CONST;
    else if (k < NTOK)  Sc[(size_t)b * NTOK + k] = wv[j] * itot;
  }
}

extern "C" void kernel_launch(void* const* d_in, const int* in_sizes, int n_in,
                              void* d_out, int out_size, void* d_ws, size_t ws_size,
                              hipStream_t stream) {
  (void)in_sizes; (void)n_in; (void)out_size; (void)ws_size;
  const float* x      = (const float*)d_in[0];   // f32 inputs
  const float* qkv_w  = (const float*)d_in[1];
  const float* proj_w = (const float*)d_in[2];
  const float* proj_b = (const float*)d_in[3];
  float* out    = (float*)d_out;                 // f32 outputs
  float* scores = out + (size_t)MROWS * CDIM;

  // Scratch in d_ws only (57.1 MB proven OK). Scores partials reuse AO after proj.
  const size_t qN  = (size_t)NBH * NTOK * HD;
  const size_t vtN = (size_t)NBH * HD * NP;
  unsigned short* Q  = (unsigned short*)d_ws;
  unsigned short* K  = Q + qN;
  unsigned short* Vt = K + qN;
  unsigned short* AO = Vt + vtN;
  // After proj consumes AO, its 14.2 MB region hosts the f32 score partials (0.9 MB).
  float* SigPart = (float*)AO;
  float* VnPart  = SigPart + (size_t)NBH * NP;

  gemm_nt<0, float, float><<<dim3(73, 18), 256, 0, stream>>>(
      x, qkv_w, MROWS, CDIM, Q, K, Vt, nullptr, nullptr);
  attn_kernel<<<dim3(10, NBH), 256, 0, stream>>>(Q, K, Vt, AO);
  gemm_nt<1, unsigned short, float><<<dim3(73, 6), 256, 0, stream>>>(
      AO, proj_w, MROWS, CDIM, nullptr, nullptr, nullptr, out, proj_b);
  scores_partial<<<dim3(NBH), 256, 0, stream>>>(Q, K, Vt, SigPart, VnPart);
  scores_final<<<dim3(NB), 256, 0, stream>>>(SigPart, VnPart, scores);
}

// Round 8
// 393.871 us; speedup vs baseline: 2.8205x; 1.3462x over previous
//
#include <hip/hip_runtime.h>
#include <stdint.h>

#define HEADS 12
#define HD 64
#define NB 16
#define NTOK 577
#define NP 592                 // padded token count for Vt rows (16B-aligned)
#define CDIM 768
#define MROWS (NB * NTOK)      // 9232
#define NBH (NB * HEADS)       // 192
#define ATT_SCALE 0.125f       // 64^-0.5
#define LOG2E 1.4426950408889634f
#define CLS_CONST 9999.0f

typedef short s16x8 __attribute__((ext_vector_type(8)));
typedef __bf16 bf16x8 __attribute__((ext_vector_type(8)));
typedef __bf16 bf16x4 __attribute__((ext_vector_type(4)));
typedef float f32x4 __attribute__((ext_vector_type(4)));

__device__ inline bf16x8 as_bf16(s16x8 v) { union { s16x8 s; bf16x8 b; } u; u.s = v; return u.b; }
__device__ inline float bf2f(unsigned short u) { union { unsigned int i; float f; } v; v.i = ((unsigned int)u) << 16; return v.f; }
__device__ inline unsigned short f2bf(float f) {
  union { float f; unsigned int i; } v; v.f = f;
  return (unsigned short)((v.i + 0x7FFFu + ((v.i >> 16) & 1u)) >> 16);
}
__device__ inline void cvt_store8(unsigned char* dst, f32x4 v) {
  bf16x4 b;
  b[0] = (__bf16)v[0]; b[1] = (__bf16)v[1]; b[2] = (__bf16)v[2]; b[3] = (__bf16)v[3];
  *reinterpret_cast<bf16x4*>(dst) = b;
}

// ---------------- f32 -> bf16 bulk convert (3 segments in one kernel) ----------------
__device__ inline void cvt_seg(const float* __restrict__ s, unsigned short* __restrict__ d,
                               int n8, int gtid, int gstride) {
  for (int i = gtid; i < n8; i += gstride) {
    f32x4 a = reinterpret_cast<const f32x4*>(s)[i * 2];
    f32x4 b = reinterpret_cast<const f32x4*>(s)[i * 2 + 1];
    union { bf16x8 v; s16x8 h; } u;
    u.v[0] = (__bf16)a[0]; u.v[1] = (__bf16)a[1]; u.v[2] = (__bf16)a[2]; u.v[3] = (__bf16)a[3];
    u.v[4] = (__bf16)b[0]; u.v[5] = (__bf16)b[1]; u.v[6] = (__bf16)b[2]; u.v[7] = (__bf16)b[3];
    reinterpret_cast<s16x8*>(d)[i] = u.h;
  }
}
__global__ __launch_bounds__(256) void cvt3_kernel(
    const float* sa, unsigned short* da, int na8,
    const float* sb, unsigned short* db, int nb8,
    const float* sc, unsigned short* dc, int nc8)
{
  const int gtid = blockIdx.x * 256 + threadIdx.x;
  const int gs = gridDim.x * 256;
  cvt_seg(sa, da, na8, gtid, gs);
  cvt_seg(sb, db, nb8, gtid, gs);
  cvt_seg(sc, dc, nc8, gtid, gs);
}

// Stage one 128x64 operand tile (f32 or bf16 source) into swizzled bf16 LDS.
template<typename T>
__device__ inline void stage_tile(unsigned char* dst, const T* src, int row0, int rowMax,
                                  int K, int k0, int tid) {
  if constexpr (sizeof(T) == 4) {
    #pragma unroll
    for (int i = 0; i < 8; ++i) {
      int c = tid + i * 256;
      int row = c >> 4, col4 = c & 15;
      int off = (row * 128 + col4 * 8) ^ ((row & 7) << 4);
      f32x4 v = {};
      if (row0 + row < rowMax)
        v = *reinterpret_cast<const f32x4*>((const float*)src + (size_t)(row0 + row) * K + k0 + col4 * 4);
      cvt_store8(dst + off, v);
    }
  } else {
    #pragma unroll
    for (int i = 0; i < 4; ++i) {
      int c = tid + i * 256;
      int row = c >> 3, col = c & 7;
      int off = (row * 128 + col * 16) ^ ((row & 7) << 4);
      s16x8 v = {};
      if (row0 + row < rowMax)
        v = *reinterpret_cast<const s16x8*>((const unsigned short*)src + (size_t)(row0 + row) * K + k0 + col * 8);
      *reinterpret_cast<s16x8*>(dst + off) = v;
    }
  }
}

// ---------------- GEMM (NT): C[M,N] = A[M,K] @ B[N,K]^T, MFMA bf16 ----------------
// 1D grid, XCD-chunked super-tiling: logical order = super-rows of 8 M-tiles x all
// N-tiles; physical bid -> logical via (bid&7)*cpx + bid>>3 so each XCD gets a
// contiguous logical chunk (A-slice ~2MB + B fit its private 4MB L2).
// MODE 0: scatter epilogue to Q/K/Vt (bf16).  MODE 1: +bias epilogue -> f32 Out.
template<int MODE, typename ATy, typename BTy>
__global__ __launch_bounds__(256) void gemm_nt(
    const ATy* __restrict__ A, const BTy* __restrict__ Bw,
    int M, int K, int mtiles, int ntiles,
    unsigned short* __restrict__ Qo, unsigned short* __restrict__ Ko,
    unsigned short* __restrict__ Vt,
    float* __restrict__ Out, const float* __restrict__ bias)
{
  const int cpx = gridDim.x >> 3;            // grid is a multiple of 8
  const int lg = (blockIdx.x & 7) * cpx + (blockIdx.x >> 3);
  const int per_sr = ntiles << 3;
  const int sr = lg / per_sr, rem = lg - sr * per_sr;
  const int nt = rem >> 3, mt = sr * 8 + (rem & 7);
  if (mt >= mtiles) return;                  // uniform whole-block exit (pre-barrier)
  const int m0 = mt * 128, n0 = nt * 128;

  __shared__ __align__(16) unsigned char As[128 * 128];
  __shared__ __align__(16) unsigned char Bs[128 * 128];
  const int tid = threadIdx.x;
  const int lane = tid & 63, w = tid >> 6;
  const int r = lane & 15, g = lane >> 4;
  const int wr = (w >> 1) * 64, wc = (w & 1) * 64;
  f32x4 acc[4][4] = {};

  for (int k0 = 0; k0 < K; k0 += 64) {
    stage_tile(As, A,  m0, M,       K, k0, tid);
    stage_tile(Bs, Bw, n0, 1 << 30, K, k0, tid);   // B rows are always full tiles
    __syncthreads();

    s16x8 af[4][2], bf[4][2];
    #pragma unroll
    for (int mi = 0; mi < 4; ++mi) {
      int row = wr + mi * 16 + r;
      #pragma unroll
      for (int ks = 0; ks < 2; ++ks)
        af[mi][ks] = *reinterpret_cast<const s16x8*>(
            As + ((row * 128 + ks * 64 + g * 16) ^ ((row & 7) << 4)));
    }
    #pragma unroll
    for (int ni = 0; ni < 4; ++ni) {
      int row = wc + ni * 16 + r;
      #pragma unroll
      for (int ks = 0; ks < 2; ++ks)
        bf[ni][ks] = *reinterpret_cast<const s16x8*>(
            Bs + ((row * 128 + ks * 64 + g * 16) ^ ((row & 7) << 4)));
    }
    #pragma unroll
    for (int mi = 0; mi < 4; ++mi)
      #pragma unroll
      for (int ni = 0; ni < 4; ++ni) {
        acc[mi][ni] = __builtin_amdgcn_mfma_f32_16x16x32_bf16(
            as_bf16(af[mi][0]), as_bf16(bf[ni][0]), acc[mi][ni], 0, 0, 0);
        acc[mi][ni] = __builtin_amdgcn_mfma_f32_16x16x32_bf16(
            as_bf16(af[mi][1]), as_bf16(bf[ni][1]), acc[mi][ni], 0, 0, 0);
      }
    __syncthreads();
  }

  // ---- epilogue.  C/D layout: col = lane&15 (r), row = (lane>>4)*4 + reg ----
  #pragma unroll
  for (int mi = 0; mi < 4; ++mi) {
    #pragma unroll
    for (int ni = 0; ni < 4; ++ni) {
      int gc = n0 + wc + ni * 16 + r;
      #pragma unroll
      for (int i = 0; i < 4; ++i) {
        int gr = m0 + wr + mi * 16 + g * 4 + i;
        if (gr >= M) continue;
        float val = acc[mi][ni][i];
        if (MODE == 0) {
          int b = gr / NTOK, n = gr - b * NTOK;
          int which = gc / CDIM, rem2 = gc - which * CDIM;
          int h = rem2 >> 6, d = rem2 & 63;
          int bh = b * HEADS + h;
          unsigned short bv = f2bf(val);
          if (which == 0)      Qo[((size_t)bh * NTOK + n) * HD + d] = bv;
          else if (which == 1) Ko[((size_t)bh * NTOK + n) * HD + d] = bv;
          else                 Vt[((size_t)bh * HD + d) * NP + n] = bv;
        } else {
          Out[(size_t)gr * CDIM + gc] = val + bias[gc];   // f32 store
        }
      }
    }
  }
}

// ---------------- Flash attention: per (b,h), 64 q-rows per block (4 waves x 16) --------
__global__ __launch_bounds__(256) void attn_kernel(
    const unsigned short* __restrict__ Q, const unsigned short* __restrict__ Kd,
    const unsigned short* __restrict__ Vt, unsigned short* __restrict__ AO)
{
  __shared__ __align__(16) unsigned char Pl[4][2048];
  const int qt = blockIdx.x;
  const int bh = blockIdx.y;
  const int tid = threadIdx.x;
  const int w = tid >> 6, lane = tid & 63;
  const int r = lane & 15, g = lane >> 4;
  const int q0 = qt * 64 + w * 16;
  const unsigned short* Qb = Q + (size_t)bh * NTOK * HD;
  const unsigned short* Kb = Kd + (size_t)bh * NTOK * HD;
  const unsigned short* Vb = Vt + (size_t)bh * HD * NP;
  unsigned char* P = Pl[w];

  int qr = q0 + r; if (qr > NTOK - 1) qr = NTOK - 1;
  s16x8 aq0 = *reinterpret_cast<const s16x8*>(Qb + (size_t)qr * HD + g * 8);
  s16x8 aq1 = *reinterpret_cast<const s16x8*>(Qb + (size_t)qr * HD + 32 + g * 8);

  f32x4 O[4] = {};
  float m2[4], l[4];
  #pragma unroll
  for (int i = 0; i < 4; ++i) { m2[i] = -3.0e38f; l[i] = 0.f; }
  const float sl = ATT_SCALE * LOG2E;

  for (int kt = 0; kt < 10; ++kt) {
    const int kb = kt * 64;
    f32x4 s[4] = {};
    #pragma unroll
    for (int f = 0; f < 4; ++f) {
      int kk = kb + f * 16 + r; if (kk > NTOK - 1) kk = NTOK - 1;
      s16x8 b0 = *reinterpret_cast<const s16x8*>(Kb + (size_t)kk * HD + g * 8);
      s16x8 b1 = *reinterpret_cast<const s16x8*>(Kb + (size_t)kk * HD + 32 + g * 8);
      s[f] = __builtin_amdgcn_mfma_f32_16x16x32_bf16(as_bf16(aq0), as_bf16(b0), s[f], 0, 0, 0);
      s[f] = __builtin_amdgcn_mfma_f32_16x16x32_bf16(as_bf16(aq1), as_bf16(b1), s[f], 0, 0, 0);
    }
    float rmax[4];
    #pragma unroll
    for (int i = 0; i < 4; ++i) rmax[i] = -3.0e38f;
    #pragma unroll
    for (int f = 0; f < 4; ++f) {
      const bool valid = (kb + f * 16 + r) < NTOK;
      #pragma unroll
      for (int i = 0; i < 4; ++i) {
        float v = valid ? s[f][i] * sl : -3.0e38f;
        s[f][i] = v;
        rmax[i] = fmaxf(rmax[i], v);
      }
    }
    #pragma unroll
    for (int off = 1; off < 16; off <<= 1)
      #pragma unroll
      for (int i = 0; i < 4; ++i) rmax[i] = fmaxf(rmax[i], __shfl_xor(rmax[i], off, 64));

    float alpha[4], rs[4];
    #pragma unroll
    for (int i = 0; i < 4; ++i) {
      float mn = fmaxf(m2[i], rmax[i]);
      alpha[i] = exp2f(fminf(m2[i] - mn, 0.f));
      m2[i] = mn;
      rs[i] = 0.f;
    }
    #pragma unroll
    for (int f = 0; f < 4; ++f) {
      #pragma unroll
      for (int i = 0; i < 4; ++i) {
        float p = exp2f(fminf(s[f][i] - m2[i], 0.f));
        rs[i] += p;
        int prow = g * 4 + i;
        int boff = (prow * 128 + (f * 16 + r) * 2) ^ ((prow & 7) << 4);
        *reinterpret_cast<unsigned short*>(P + boff) = f2bf(p);
      }
    }
    #pragma unroll
    for (int off = 1; off < 16; off <<= 1)
      #pragma unroll
      for (int i = 0; i < 4; ++i) rs[i] += __shfl_xor(rs[i], off, 64);
    #pragma unroll
    for (int i = 0; i < 4; ++i) l[i] = l[i] * alpha[i] + rs[i];
    #pragma unroll
    for (int f = 0; f < 4; ++f)
      #pragma unroll
      for (int i = 0; i < 4; ++i) O[f][i] *= alpha[i];

    #pragma unroll
    for (int ks = 0; ks < 2; ++ks) {
      s16x8 pa = *reinterpret_cast<const s16x8*>(
          P + ((r * 128 + ks * 64 + g * 16) ^ ((r & 7) << 4)));
      int nn = kb + ks * 32 + g * 8; if (nn >= NTOK) nn = 0;   // masked keys have p=0
      #pragma unroll
      for (int f = 0; f < 4; ++f) {
        s16x8 bv = *reinterpret_cast<const s16x8*>(Vb + (size_t)(f * 16 + r) * NP + nn);
        O[f] = __builtin_amdgcn_mfma_f32_16x16x32_bf16(as_bf16(pa), as_bf16(bv), O[f], 0, 0, 0);
      }
    }
  }

  const int b = bh / HEADS, h = bh - b * HEADS;
  float inv[4];
  #pragma unroll
  for (int i = 0; i < 4; ++i) inv[i] = 1.0f / fmaxf(l[i], 1e-20f);
  #pragma unroll
  for (int f = 0; f < 4; ++f)
    #pragma unroll
    for (int i = 0; i < 4; ++i) {
      int row = q0 + g * 4 + i;
      if (row < NTOK)
        AO[((size_t)(b * NTOK + row)) * CDIM + h * HD + f * 16 + r] = f2bf(O[f][i] * inv[i]);
    }
}

// ---------------- Scores phase A: per (b,h) CLS-softmax + partial v-norm^2 ------------
__global__ __launch_bounds__(256) void scores_partial(
    const unsigned short* __restrict__ Q, const unsigned short* __restrict__ Kd,
    const unsigned short* __restrict__ Vt,
    float* __restrict__ SigPart, float* __restrict__ VnPart)
{
  const int bh = blockIdx.x;
  const int tid = threadIdx.x;
  __shared__ float qv[64];
  __shared__ float red[256];
  if (tid < 64) qv[tid] = bf2f(Q[(size_t)bh * NTOK * HD + tid]);
  __syncthreads();
  const float sl = ATT_SCALE * LOG2E;
  const unsigned short* Kb = Kd + (size_t)bh * NTOK * HD;
  const unsigned short* Vb = Vt + (size_t)bh * HD * NP;

  float sv[3];
  #pragma unroll
  for (int j = 0; j < 3; ++j) {
    int k = tid + j * 256;
    float s = -3.0e38f;
    if (k < NTOK) {
      const unsigned short* kr = Kb + (size_t)k * HD;
      float acc = 0.f;
      #pragma unroll
      for (int d8 = 0; d8 < 8; ++d8) {
        s16x8 kv = *reinterpret_cast<const s16x8*>(kr + d8 * 8);
        #pragma unroll
        for (int e = 0; e < 8; ++e) acc += qv[d8 * 8 + e] * bf2f((unsigned short)kv[e]);
      }
      s = acc * sl;
    }
    sv[j] = s;
  }
  float lm = fmaxf(fmaxf(sv[0], sv[1]), sv[2]);
  red[tid] = lm; __syncthreads();
  for (int st = 128; st > 0; st >>= 1) {
    if (tid < st) red[tid] = fmaxf(red[tid], red[tid + st]);
    __syncthreads();
  }
  float mx = red[0]; __syncthreads();
  float pv[3], ps = 0.f;
  #pragma unroll
  for (int j = 0; j < 3; ++j) { pv[j] = exp2f(fminf(sv[j] - mx, 0.f)); ps += pv[j]; }
  red[tid] = ps; __syncthreads();
  for (int st = 128; st > 0; st >>= 1) {
    if (tid < st) red[tid] += red[tid + st];
    __syncthreads();
  }
  const float itot = 1.f / fmaxf(red[0], 1e-20f);
  #pragma unroll
  for (int j = 0; j < 3; ++j) {
    int k = tid + j * 256;
    if (k < NTOK) SigPart[(size_t)bh * NP + k] = pv[j] * itot;
  }
  float vacc[3] = {0.f, 0.f, 0.f};
  for (int d = 0; d < HD; ++d) {
    const unsigned short* vr = Vb + (size_t)d * NP;
    #pragma unroll
    for (int j = 0; j < 3; ++j) {
      int k = tid + j * 256;
      if (k < NTOK) { float v = bf2f(vr[k]); vacc[j] += v * v; }
    }
  }
  #pragma unroll
  for (int j = 0; j < 3; ++j) {
    int k = tid + j * 256;
    if (k < NTOK) VnPart[(size_t)bh * NP + k] = vacc[j];
  }
}

// ---------------- Scores phase B: combine heads, normalize, write f32 ------------------
__global__ __launch_bounds__(256) void scores_final(
    const float* __restrict__ SigPart, const float* __restrict__ VnPart,
    float* __restrict__ Sc)
{
  const int b = blockIdx.x;
  const int tid = threadIdx.x;
  __shared__ float red[256];
  float wv[3]; float part = 0.f;
  #pragma unroll
  for (int j = 0; j < 3; ++j) {
    int k = tid + j * 256;
    wv[j] = 0.f;
    if (k < NTOK) {
      float sig = 0.f, vn = 0.f;
      #pragma unroll
      for (int h = 0; h < HEADS; ++h) {
        sig += SigPart[((size_t)(b * HEADS + h)) * NP + k];
        vn  += VnPart [((size_t)(b * HEADS + h)) * NP + k];
      }
      wv[j] = sig * sqrtf(vn);
      if (k >= 1) part += wv[j];
    }
  }
  red[tid] = part; __syncthreads();
  for (int st = 128; st > 0; st >>= 1) {
    if (tid < st) red[tid] += red[tid + st];
    __syncthreads();
  }
  const float itot = 1.f / fmaxf(red[0], 1e-20f);
  #pragma unroll
  for (int j = 0; j < 3; ++j) {
    int k = tid + j * 256;
    if (k == 0)         Sc[(size_t)b * NTOK] = CLS_CONST;
    else if (k < NTOK)  Sc[(size_t)b * NTOK + k] = wv[j] * itot;
  }
}

extern "C" void kernel_launch(void* const* d_in, const int* in_sizes, int n_in,
                              void* d_out, int out_size, void* d_ws, size_t ws_size,
                              hipStream_t stream) {
  (void)in_sizes; (void)n_in; (void)out_size;
  const float* x      = (const float*)d_in[0];
  const float* qkv_w  = (const float*)d_in[1];
  const float* proj_w = (const float*)d_in[2];
  const float* proj_b = (const float*)d_in[3];
  float* out    = (float*)d_out;
  float* scores = out + (size_t)MROWS * CDIM;

  const size_t xN   = (size_t)MROWS * CDIM;       // 7,090,176 (also AO elems)
  const size_t qwN  = (size_t)(3 * CDIM) * CDIM;  // 1,769,472
  const size_t pwN  = (size_t)CDIM * CDIM;        //   589,824
  const size_t qN   = (size_t)NBH * NTOK * HD;    // 7,090,176
  const size_t vtN  = (size_t)NBH * HD * NP;      // 7,274,496
  const size_t need = (xN + qwN + pwN + 2 * qN + vtN) * 2;  // 61.8 MB

  if (ws_size >= need) {
    // bf16 everything: xb (later reused as AO), qkvwb (later reused as score
    // partials), projwb, Q, K, Vt.
    unsigned short* xb     = (unsigned short*)d_ws;
    unsigned short* qkvwb  = xb + xN;
    unsigned short* projwb = qkvwb + qwN;
    unsigned short* Q      = projwb + pwN;
    unsigned short* K      = Q + qN;
    unsigned short* Vt     = K + qN;
    unsigned short* AO     = xb;                     // x dead after QKV GEMM
    float* SigPart = (float*)qkvwb;                  // qkv_w dead after QKV GEMM
    float* VnPart  = SigPart + (size_t)NBH * NP;

    cvt3_kernel<<<2048, 256, 0, stream>>>(
        x, xb, (int)(xN / 8), qkv_w, qkvwb, (int)(qwN / 8), proj_w, projwb, (int)(pwN / 8));
    gemm_nt<0, unsigned short, unsigned short><<<1440, 256, 0, stream>>>(
        xb, qkvwb, MROWS, CDIM, 73, 18, Q, K, Vt, nullptr, nullptr);
    attn_kernel<<<dim3(10, NBH), 256, 0, stream>>>(Q, K, Vt, AO);
    gemm_nt<1, unsigned short, unsigned short><<<480, 256, 0, stream>>>(
        AO, projwb, MROWS, CDIM, 73, 6, nullptr, nullptr, nullptr, out, proj_b);
    scores_partial<<<dim3(NBH), 256, 0, stream>>>(Q, K, Vt, SigPart, VnPart);
    scores_final<<<dim3(NB), 256, 0, stream>>>(SigPart, VnPart, scores);
  } else {
    // Fallback: proven round-7 layout (57.1 MB), f32 staging.
    unsigned short* Q  = (unsigned short*)d_ws;
    unsigned short* K  = Q + qN;
    unsigned short* Vt = K + qN;
    unsigned short* AO = Vt + vtN;
    float* SigPart = (float*)AO;                     // AO dead after proj
    float* VnPart  = SigPart + (size_t)NBH * NP;

    gemm_nt<0, float, float><<<1440, 256, 0, stream>>>(
        x, qkv_w, MROWS, CDIM, 73, 18, Q, K, Vt, nullptr, nullptr);
    attn_kernel<<<dim3(10, NBH), 256, 0, stream>>>(Q, K, Vt, AO);
    gemm_nt<1, unsigned short, float><<<480, 256, 0, stream>>>(
        AO, proj_w, MROWS, CDIM, 73, 6, nullptr, nullptr, nullptr, out, proj_b);
    scores_partial<<<dim3(NBH), 256, 0, stream>>>(Q, K, Vt, SigPart, VnPart);
    scores_final<<<dim3(NB), 256, 0, stream>>>(SigPart, VnPart, scores);
  }
}

// Round 9
// 387.415 us; speedup vs baseline: 2.8675x; 1.0167x over previous
//
#include <hip/hip_runtime.h>
#include <stdint.h>

#define HEADS 12
#define HD 64
#define NB 16
#define NTOK 577
#define NP 592                 // padded token count for Vt rows (16B-aligned)
#define CDIM 768
#define MROWS (NB * NTOK)      // 9232
#define NBH (NB * HEADS)       // 192
#define ATT_SCALE 0.125f       // 64^-0.5
#define LOG2E 1.4426950408889634f
#define CLS_CONST 9999.0f

typedef short s16x8 __attribute__((ext_vector_type(8)));
typedef __bf16 bf16x8 __attribute__((ext_vector_type(8)));
typedef __bf16 bf16x4 __attribute__((ext_vector_type(4)));
typedef float f32x4 __attribute__((ext_vector_type(4)));

__device__ inline bf16x8 as_bf16(s16x8 v) { union { s16x8 s; bf16x8 b; } u; u.s = v; return u.b; }
__device__ inline float bf2f(unsigned short u) { union { unsigned int i; float f; } v; v.i = ((unsigned int)u) << 16; return v.f; }
__device__ inline unsigned short f2bf(float f) {
  union { float f; unsigned int i; } v; v.f = f;
  return (unsigned short)((v.i + 0x7FFFu + ((v.i >> 16) & 1u)) >> 16);
}
__device__ inline unsigned short hbf(float f) {       // hardware RNE convert
  union { __bf16 b; unsigned short u; } c; c.b = (__bf16)f; return c.u;
}
__device__ inline void cvt_store8(unsigned char* dst, f32x4 v) {
  bf16x4 b;
  b[0] = (__bf16)v[0]; b[1] = (__bf16)v[1]; b[2] = (__bf16)v[2]; b[3] = (__bf16)v[3];
  *reinterpret_cast<bf16x4*>(dst) = b;
}

// ---------------- f32 -> bf16 bulk convert (3 segments in one kernel) ----------------
__device__ inline void cvt_seg(const float* __restrict__ s, unsigned short* __restrict__ d,
                               int n8, int gtid, int gstride) {
  for (int i = gtid; i < n8; i += gstride) {
    f32x4 a = reinterpret_cast<const f32x4*>(s)[i * 2];
    f32x4 b = reinterpret_cast<const f32x4*>(s)[i * 2 + 1];
    union { bf16x8 v; s16x8 h; } u;
    u.v[0] = (__bf16)a[0]; u.v[1] = (__bf16)a[1]; u.v[2] = (__bf16)a[2]; u.v[3] = (__bf16)a[3];
    u.v[4] = (__bf16)b[0]; u.v[5] = (__bf16)b[1]; u.v[6] = (__bf16)b[2]; u.v[7] = (__bf16)b[3];
    reinterpret_cast<s16x8*>(d)[i] = u.h;
  }
}
__global__ __launch_bounds__(256) void cvt3_kernel(
    const float* sa, unsigned short* da, int na8,
    const float* sb, unsigned short* db, int nb8,
    const float* sc, unsigned short* dc, int nc8)
{
  const int gtid = blockIdx.x * 256 + threadIdx.x;
  const int gs = gridDim.x * 256;
  cvt_seg(sa, da, na8, gtid, gs);
  cvt_seg(sb, db, nb8, gtid, gs);
  cvt_seg(sc, dc, nc8, gtid, gs);
}

// Stage one 128x64 operand tile (f32 or bf16 source) into swizzled bf16 LDS.
template<typename T>
__device__ inline void stage_tile(unsigned char* dst, const T* src, int row0, int rowMax,
                                  int K, int k0, int tid) {
  if constexpr (sizeof(T) == 4) {
    #pragma unroll
    for (int i = 0; i < 8; ++i) {
      int c = tid + i * 256;
      int row = c >> 4, col4 = c & 15;
      int off = (row * 128 + col4 * 8) ^ ((row & 7) << 4);
      f32x4 v = {};
      if (row0 + row < rowMax)
        v = *reinterpret_cast<const f32x4*>((const float*)src + (size_t)(row0 + row) * K + k0 + col4 * 4);
      cvt_store8(dst + off, v);
    }
  } else {
    #pragma unroll
    for (int i = 0; i < 4; ++i) {
      int c = tid + i * 256;
      int row = c >> 3, col = c & 7;
      int off = (row * 128 + col * 16) ^ ((row & 7) << 4);
      s16x8 v = {};
      if (row0 + row < rowMax)
        v = *reinterpret_cast<const s16x8*>((const unsigned short*)src + (size_t)(row0 + row) * K + k0 + col * 8);
      *reinterpret_cast<s16x8*>(dst + off) = v;
    }
  }
}

// ---------------- GEMM (NT): C[M,N] = A[M,K] @ B[N,K]^T, MFMA bf16 ----------------
// 1D grid, XCD-chunked super-tiling (see round 7 notes).
template<int MODE, typename ATy, typename BTy>
__global__ __launch_bounds__(256) void gemm_nt(
    const ATy* __restrict__ A, const BTy* __restrict__ Bw,
    int M, int K, int mtiles, int ntiles,
    unsigned short* __restrict__ Qo, unsigned short* __restrict__ Ko,
    unsigned short* __restrict__ Vt,
    float* __restrict__ Out, const float* __restrict__ bias)
{
  const int cpx = gridDim.x >> 3;            // grid is a multiple of 8
  const int lg = (blockIdx.x & 7) * cpx + (blockIdx.x >> 3);
  const int per_sr = ntiles << 3;
  const int sr = lg / per_sr, rem = lg - sr * per_sr;
  const int nt = rem >> 3, mt = sr * 8 + (rem & 7);
  if (mt >= mtiles) return;                  // uniform whole-block exit (pre-barrier)
  const int m0 = mt * 128, n0 = nt * 128;

  __shared__ __align__(16) unsigned char As[128 * 128];
  __shared__ __align__(16) unsigned char Bs[128 * 128];
  const int tid = threadIdx.x;
  const int lane = tid & 63, w = tid >> 6;
  const int r = lane & 15, g = lane >> 4;
  const int wr = (w >> 1) * 64, wc = (w & 1) * 64;
  f32x4 acc[4][4] = {};

  for (int k0 = 0; k0 < K; k0 += 64) {
    stage_tile(As, A,  m0, M,       K, k0, tid);
    stage_tile(Bs, Bw, n0, 1 << 30, K, k0, tid);   // B rows are always full tiles
    __syncthreads();

    s16x8 af[4][2], bf[4][2];
    #pragma unroll
    for (int mi = 0; mi < 4; ++mi) {
      int row = wr + mi * 16 + r;
      #pragma unroll
      for (int ks = 0; ks < 2; ++ks)
        af[mi][ks] = *reinterpret_cast<const s16x8*>(
            As + ((row * 128 + ks * 64 + g * 16) ^ ((row & 7) << 4)));
    }
    #pragma unroll
    for (int ni = 0; ni < 4; ++ni) {
      int row = wc + ni * 16 + r;
      #pragma unroll
      for (int ks = 0; ks < 2; ++ks)
        bf[ni][ks] = *reinterpret_cast<const s16x8*>(
            Bs + ((row * 128 + ks * 64 + g * 16) ^ ((row & 7) << 4)));
    }
    #pragma unroll
    for (int mi = 0; mi < 4; ++mi)
      #pragma unroll
      for (int ni = 0; ni < 4; ++ni) {
        acc[mi][ni] = __builtin_amdgcn_mfma_f32_16x16x32_bf16(
            as_bf16(af[mi][0]), as_bf16(bf[ni][0]), acc[mi][ni], 0, 0, 0);
        acc[mi][ni] = __builtin_amdgcn_mfma_f32_16x16x32_bf16(
            as_bf16(af[mi][1]), as_bf16(bf[ni][1]), acc[mi][ni], 0, 0, 0);
      }
    __syncthreads();
  }

  // ---- epilogue.  C/D layout: col = lane&15 (r), row = (lane>>4)*4 + reg ----
  #pragma unroll
  for (int mi = 0; mi < 4; ++mi) {
    #pragma unroll
    for (int ni = 0; ni < 4; ++ni) {
      int gc = n0 + wc + ni * 16 + r;
      #pragma unroll
      for (int i = 0; i < 4; ++i) {
        int gr = m0 + wr + mi * 16 + g * 4 + i;
        if (gr >= M) continue;
        float val = acc[mi][ni][i];
        if (MODE == 0) {
          int b = gr / NTOK, n = gr - b * NTOK;
          int which = gc / CDIM, rem2 = gc - which * CDIM;
          int h = rem2 >> 6, d = rem2 & 63;
          int bh = b * HEADS + h;
          unsigned short bv = f2bf(val);
          if (which == 0)      Qo[((size_t)bh * NTOK + n) * HD + d] = bv;
          else if (which == 1) Ko[((size_t)bh * NTOK + n) * HD + d] = bv;
          else                 Vt[((size_t)bh * HD + d) * NP + n] = bv;
        } else {
          Out[(size_t)gr * CDIM + gc] = val + bias[gc];   // f32 store
        }
      }
    }
  }
}

// ---------------- Flash attention: per (b,h), 64 q-rows per block (4 waves x 16) --------
// 1D grid with XCD swizzle: all 10 q-tile blocks of one head land on the SAME XCD,
// so K/V are fetched from HBM once per head and served from that XCD's L2 after.
__global__ __launch_bounds__(256) void attn_kernel(
    const unsigned short* __restrict__ Q, const unsigned short* __restrict__ Kd,
    const unsigned short* __restrict__ Vt, unsigned short* __restrict__ AO)
{
  const int cpx = gridDim.x >> 3;             // 1920/8 = 240
  const int lg = (blockIdx.x & 7) * cpx + (blockIdx.x >> 3);
  const int bh = lg / 10, qt = lg - bh * 10;

  __shared__ __align__(16) unsigned char Pl[4][2048];
  const int tid = threadIdx.x;
  const int w = tid >> 6, lane = tid & 63;
  const int r = lane & 15, g = lane >> 4;
  const int q0 = qt * 64 + w * 16;
  const unsigned short* Qb = Q + (size_t)bh * NTOK * HD;
  const unsigned short* Kb = Kd + (size_t)bh * NTOK * HD;
  const unsigned short* Vb = Vt + (size_t)bh * HD * NP;
  unsigned char* P = Pl[w];

  int qr = q0 + r; if (qr > NTOK - 1) qr = NTOK - 1;
  s16x8 aq0 = *reinterpret_cast<const s16x8*>(Qb + (size_t)qr * HD + g * 8);
  s16x8 aq1 = *reinterpret_cast<const s16x8*>(Qb + (size_t)qr * HD + 32 + g * 8);

  f32x4 O[4] = {};
  float m2[4], l[4];
  #pragma unroll
  for (int i = 0; i < 4; ++i) { m2[i] = -3.0e38f; l[i] = 0.f; }
  const float sl = ATT_SCALE * LOG2E;

  for (int kt = 0; kt < 10; ++kt) {
    const int kb = kt * 64;
    f32x4 s[4] = {};
    #pragma unroll
    for (int f = 0; f < 4; ++f) {
      int kk = kb + f * 16 + r; if (kk > NTOK - 1) kk = NTOK - 1;
      s16x8 b0 = *reinterpret_cast<const s16x8*>(Kb + (size_t)kk * HD + g * 8);
      s16x8 b1 = *reinterpret_cast<const s16x8*>(Kb + (size_t)kk * HD + 32 + g * 8);
      s[f] = __builtin_amdgcn_mfma_f32_16x16x32_bf16(as_bf16(aq0), as_bf16(b0), s[f], 0, 0, 0);
      s[f] = __builtin_amdgcn_mfma_f32_16x16x32_bf16(as_bf16(aq1), as_bf16(b1), s[f], 0, 0, 0);
    }
    float rmax[4];
    #pragma unroll
    for (int i = 0; i < 4; ++i) rmax[i] = -3.0e38f;
    #pragma unroll
    for (int f = 0; f < 4; ++f) {
      const bool valid = (kb + f * 16 + r) < NTOK;
      #pragma unroll
      for (int i = 0; i < 4; ++i) {
        float v = valid ? s[f][i] * sl : -3.0e38f;
        s[f][i] = v;
        rmax[i] = fmaxf(rmax[i], v);
      }
    }
    #pragma unroll
    for (int off = 1; off < 16; off <<= 1)
      #pragma unroll
      for (int i = 0; i < 4; ++i) rmax[i] = fmaxf(rmax[i], __shfl_xor(rmax[i], off, 64));

    float alpha[4], rs[4];
    #pragma unroll
    for (int i = 0; i < 4; ++i) {
      float mn = fmaxf(m2[i], rmax[i]);
      alpha[i] = exp2f(m2[i] - mn);            // m2 <= mn by construction
      m2[i] = mn;
      rs[i] = 0.f;
    }
    #pragma unroll
    for (int f = 0; f < 4; ++f) {
      #pragma unroll
      for (int i = 0; i < 4; ++i) {
        float p = exp2f(s[f][i] - m2[i]);      // s <= m2; masked keys underflow to 0
        rs[i] += p;
        int prow = g * 4 + i;
        int boff = (prow * 128 + (f * 16 + r) * 2) ^ ((prow & 7) << 4);
        *reinterpret_cast<unsigned short*>(P + boff) = hbf(p);
      }
    }
    #pragma unroll
    for (int off = 1; off < 16; off <<= 1)
      #pragma unroll
      for (int i = 0; i < 4; ++i) rs[i] += __shfl_xor(rs[i], off, 64);
    #pragma unroll
    for (int i = 0; i < 4; ++i) l[i] = l[i] * alpha[i] + rs[i];
    #pragma unroll
    for (int f = 0; f < 4; ++f)
      #pragma unroll
      for (int i = 0; i < 4; ++i) O[f][i] *= alpha[i];

    #pragma unroll
    for (int ks = 0; ks < 2; ++ks) {
      s16x8 pa = *reinterpret_cast<const s16x8*>(
          P + ((r * 128 + ks * 64 + g * 16) ^ ((r & 7) << 4)));
      int nn = kb + ks * 32 + g * 8; if (nn >= NTOK) nn = 0;   // masked keys have p=0
      #pragma unroll
      for (int f = 0; f < 4; ++f) {
        s16x8 bv = *reinterpret_cast<const s16x8*>(Vb + (size_t)(f * 16 + r) * NP + nn);
        O[f] = __builtin_amdgcn_mfma_f32_16x16x32_bf16(as_bf16(pa), as_bf16(bv), O[f], 0, 0, 0);
      }
    }
  }

  const int b = bh / HEADS, h = bh - b * HEADS;
  float inv[4];
  #pragma unroll
  for (int i = 0; i < 4; ++i) inv[i] = 1.0f / fmaxf(l[i], 1e-20f);
  #pragma unroll
  for (int f = 0; f < 4; ++f)
    #pragma unroll
    for (int i = 0; i < 4; ++i) {
      int row = q0 + g * 4 + i;
      if (row < NTOK)
        AO[((size_t)(b * NTOK + row)) * CDIM + h * HD + f * 16 + r] = hbf(O[f][i] * inv[i]);
    }
}

// ---------------- Scores phase A: per (b,h) CLS-softmax + partial v-norm^2 ------------
__global__ __launch_bounds__(256) void scores_partial(
    const unsigned short* __restrict__ Q, const unsigned short* __restrict__ Kd,
    const unsigned short* __restrict__ Vt,
    float* __restrict__ SigPart, float* __restrict__ VnPart)
{
  const int bh = blockIdx.x;
  const int tid = threadIdx.x;
  __shared__ float qv[64];
  __shared__ float red[256];
  if (tid < 64) qv[tid] = bf2f(Q[(size_t)bh * NTOK * HD + tid]);
  __syncthreads();
  const float sl = ATT_SCALE * LOG2E;
  const unsigned short* Kb = Kd + (size_t)bh * NTOK * HD;
  const unsigned short* Vb = Vt + (size_t)bh * HD * NP;

  float sv[3];
  #pragma unroll
  for (int j = 0; j < 3; ++j) {
    int k = tid + j * 256;
    float s = -3.0e38f;
    if (k < NTOK) {
      const unsigned short* kr = Kb + (size_t)k * HD;
      float acc = 0.f;
      #pragma unroll
      for (int d8 = 0; d8 < 8; ++d8) {
        s16x8 kv = *reinterpret_cast<const s16x8*>(kr + d8 * 8);
        #pragma unroll
        for (int e = 0; e < 8; ++e) acc += qv[d8 * 8 + e] * bf2f((unsigned short)kv[e]);
      }
      s = acc * sl;
    }
    sv[j] = s;
  }
  float lm = fmaxf(fmaxf(sv[0], sv[1]), sv[2]);
  red[tid] = lm; __syncthreads();
  for (int st = 128; st > 0; st >>= 1) {
    if (tid < st) red[tid] = fmaxf(red[tid], red[tid + st]);
    __syncthreads();
  }
  float mx = red[0]; __syncthreads();
  float pv[3], ps = 0.f;
  #pragma unroll
  for (int j = 0; j < 3; ++j) { pv[j] = exp2f(fminf(sv[j] - mx, 0.f)); ps += pv[j]; }
  red[tid] = ps; __syncthreads();
  for (int st = 128; st > 0; st >>= 1) {
    if (tid < st) red[tid] += red[tid + st];
    __syncthreads();
  }
  const float itot = 1.f / fmaxf(red[0], 1e-20f);
  #pragma unroll
  for (int j = 0; j < 3; ++j) {
    int k = tid + j * 256;
    if (k < NTOK) SigPart[(size_t)bh * NP + k] = pv[j] * itot;
  }
  float vacc[3] = {0.f, 0.f, 0.f};
  for (int d = 0; d < HD; ++d) {
    const unsigned short* vr = Vb + (size_t)d * NP;
    #pragma unroll
    for (int j = 0; j < 3; ++j) {
      int k = tid + j * 256;
      if (k < NTOK) { float v = bf2f(vr[k]); vacc[j] += v * v; }
    }
  }
  #pragma unroll
  for (int j = 0; j < 3; ++j) {
    int k = tid + j * 256;
    if (k < NTOK) VnPart[(size_t)bh * NP + k] = vacc[j];
  }
}

// ---------------- Scores phase B: combine heads, normalize, write f32 ------------------
__global__ __launch_bounds__(256) void scores_final(
    const float* __restrict__ SigPart, const float* __restrict__ VnPart,
    float* __restrict__ Sc)
{
  const int b = blockIdx.x;
  const int tid = threadIdx.x;
  __shared__ float red[256];
  float wv[3]; float part = 0.f;
  #pragma unroll
  for (int j = 0; j < 3; ++j) {
    int k = tid + j * 256;
    wv[j] = 0.f;
    if (k < NTOK) {
      float sig = 0.f, vn = 0.f;
      #pragma unroll
      for (int h = 0; h < HEADS; ++h) {
        sig += SigPart[((size_t)(b * HEADS + h)) * NP + k];
        vn  += VnPart [((size_t)(b * HEADS + h)) * NP + k];
      }
      wv[j] = sig * sqrtf(vn);
      if (k >= 1) part += wv[j];
    }
  }
  red[tid] = part; __syncthreads();
  for (int st = 128; st > 0; st >>= 1) {
    if (tid < st) red[tid] += red[tid + st];
    __syncthreads();
  }
  const float itot = 1.f / fmaxf(red[0], 1e-20f);
  #pragma unroll
  for (int j = 0; j < 3; ++j) {
    int k = tid + j * 256;
    if (k == 0)         Sc[(size_t)b * NTOK] = CLS_CONST;
    else if (k < NTOK)  Sc[(size_t)b * NTOK + k] = wv[j] * itot;
  }
}

extern "C" void kernel_launch(void* const* d_in, const int* in_sizes, int n_in,
                              void* d_out, int out_size, void* d_ws, size_t ws_size,
                              hipStream_t stream) {
  (void)in_sizes; (void)n_in; (void)out_size;
  const float* x      = (const float*)d_in[0];
  const float* qkv_w  = (const float*)d_in[1];
  const float* proj_w = (const float*)d_in[2];
  const float* proj_b = (const float*)d_in[3];
  float* out    = (float*)d_out;
  float* scores = out + (size_t)MROWS * CDIM;

  const size_t xN   = (size_t)MROWS * CDIM;       // 7,090,176 (also AO elems)
  const size_t qwN  = (size_t)(3 * CDIM) * CDIM;  // 1,769,472
  const size_t pwN  = (size_t)CDIM * CDIM;        //   589,824
  const size_t qN   = (size_t)NBH * NTOK * HD;    // 7,090,176
  const size_t vtN  = (size_t)NBH * HD * NP;      // 7,274,496
  const size_t need = (xN + qwN + pwN + 2 * qN + vtN) * 2;  // 61.8 MB

  if (ws_size >= need) {
    unsigned short* xb     = (unsigned short*)d_ws;
    unsigned short* qkvwb  = xb + xN;
    unsigned short* projwb = qkvwb + qwN;
    unsigned short* Q      = projwb + pwN;
    unsigned short* K      = Q + qN;
    unsigned short* Vt     = K + qN;
    unsigned short* AO     = xb;                     // x dead after QKV GEMM
    float* SigPart = (float*)qkvwb;                  // qkv_w dead after QKV GEMM
    float* VnPart  = SigPart + (size_t)NBH * NP;

    cvt3_kernel<<<2048, 256, 0, stream>>>(
        x, xb, (int)(xN / 8), qkv_w, qkvwb, (int)(qwN / 8), proj_w, projwb, (int)(pwN / 8));
    gemm_nt<0, unsigned short, unsigned short><<<1440, 256, 0, stream>>>(
        xb, qkvwb, MROWS, CDIM, 73, 18, Q, K, Vt, nullptr, nullptr);
    attn_kernel<<<1920, 256, 0, stream>>>(Q, K, Vt, AO);
    gemm_nt<1, unsigned short, unsigned short><<<480, 256, 0, stream>>>(
        AO, projwb, MROWS, CDIM, 73, 6, nullptr, nullptr, nullptr, out, proj_b);
    scores_partial<<<dim3(NBH), 256, 0, stream>>>(Q, K, Vt, SigPart, VnPart);
    scores_final<<<dim3(NB), 256, 0, stream>>>(SigPart, VnPart, scores);
  } else {
    // Fallback: proven round-7 layout (57.1 MB), f32 staging.
    unsigned short* Q  = (unsigned short*)d_ws;
    unsigned short* K  = Q + qN;
    unsigned short* Vt = K + qN;
    unsigned short* AO = Vt + vtN;
    float* SigPart = (float*)AO;                     // AO dead after proj
    float* VnPart  = SigPart + (size_t)NBH * NP;

    gemm_nt<0, float, float><<<1440, 256, 0, stream>>>(
        x, qkv_w, MROWS, CDIM, 73, 18, Q, K, Vt, nullptr, nullptr);
    attn_kernel<<<1920, 256, 0, stream>>>(Q, K, Vt, AO);
    gemm_nt<1, unsigned short, float><<<480, 256, 0, stream>>>(
        AO, proj_w, MROWS, CDIM, 73, 6, nullptr, nullptr, nullptr, out, proj_b);
    scores_partial<<<dim3(NBH), 256, 0, stream>>>(Q, K, Vt, SigPart, VnPart);
    scores_final<<<dim3(NB), 256, 0, stream>>>(SigPart, VnPart, scores);
  }
}

// Round 10
// 341.890 us; speedup vs baseline: 3.2494x; 1.1332x over previous
//
#include <hip/hip_runtime.h>
#include <stdint.h>

#define HEADS 12
#define HD 64
#define NB 16
#define NTOK 577
#define NP 592                 // padded token count for Vt rows (16B-aligned)
#define CDIM 768
#define MROWS (NB * NTOK)      // 9232
#define NBH (NB * HEADS)       // 192
#define ATT_SCALE 0.125f       // 64^-0.5
#define LOG2E 1.4426950408889634f
#define CLS_CONST 9999.0f

typedef short s16x8 __attribute__((ext_vector_type(8)));
typedef __bf16 bf16x8 __attribute__((ext_vector_type(8)));
typedef __bf16 bf16x4 __attribute__((ext_vector_type(4)));
typedef float f32x4 __attribute__((ext_vector_type(4)));

__device__ inline bf16x8 as_bf16(s16x8 v) { union { s16x8 s; bf16x8 b; } u; u.s = v; return u.b; }
__device__ inline float bf2f(unsigned short u) { union { unsigned int i; float f; } v; v.i = ((unsigned int)u) << 16; return v.f; }
__device__ inline unsigned short f2bf(float f) {
  union { float f; unsigned int i; } v; v.f = f;
  return (unsigned short)((v.i + 0x7FFFu + ((v.i >> 16) & 1u)) >> 16);
}
__device__ inline unsigned short hbf(float f) {       // hardware RNE convert
  union { __bf16 b; unsigned short u; } c; c.b = (__bf16)f; return c.u;
}
__device__ inline void cvt_store8(unsigned char* dst, f32x4 v) {
  bf16x4 b;
  b[0] = (__bf16)v[0]; b[1] = (__bf16)v[1]; b[2] = (__bf16)v[2]; b[3] = (__bf16)v[3];
  *reinterpret_cast<bf16x4*>(dst) = b;
}

// ---------------- f32 -> bf16 bulk convert (3 segments in one kernel) ----------------
__device__ inline void cvt_seg(const float* __restrict__ s, unsigned short* __restrict__ d,
                               int n8, int gtid, int gstride) {
  for (int i = gtid; i < n8; i += gstride) {
    f32x4 a = reinterpret_cast<const f32x4*>(s)[i * 2];
    f32x4 b = reinterpret_cast<const f32x4*>(s)[i * 2 + 1];
    union { bf16x8 v; s16x8 h; } u;
    u.v[0] = (__bf16)a[0]; u.v[1] = (__bf16)a[1]; u.v[2] = (__bf16)a[2]; u.v[3] = (__bf16)a[3];
    u.v[4] = (__bf16)b[0]; u.v[5] = (__bf16)b[1]; u.v[6] = (__bf16)b[2]; u.v[7] = (__bf16)b[3];
    reinterpret_cast<s16x8*>(d)[i] = u.h;
  }
}
__global__ __launch_bounds__(256) void cvt3_kernel(
    const float* sa, unsigned short* da, int na8,
    const float* sb, unsigned short* db, int nb8,
    const float* sc, unsigned short* dc, int nc8)
{
  const int gtid = blockIdx.x * 256 + threadIdx.x;
  const int gs = gridDim.x * 256;
  cvt_seg(sa, da, na8, gtid, gs);
  cvt_seg(sb, db, nb8, gtid, gs);
  cvt_seg(sc, dc, nc8, gtid, gs);
}

// ---- bf16 tile staging via global_load_lds (direct DMA; rule #21 pattern) ----
// LDS dest is LINEAR (wave-uniform base + lane*16 by HW); the XOR-swizzle is applied
// to the per-lane GLOBAL source column instead: lane l of an 8-row chunk fetches
// global col ((l&7) ^ (l>>3)) — the read-side swizzle (row&7)<<4 is its own inverse.
// OOB A-rows (last M-tile) read harmless workspace bytes; stores are masked by gr<M.
__device__ inline void stage_dma(unsigned char* dst, const unsigned short* src,
                                 int row0, int K, int k0, int w, int lane) {
  const int rsub = lane >> 3;                       // row within 8-row chunk
  const int colE = ((lane & 7) ^ rsub) * 8;         // inverse-swizzled element col
  #pragma unroll
  for (int i = 0; i < 4; ++i) {
    const int c = i * 4 + w;                        // chunk 0..15 (wave-uniform)
    const int row = c * 8 + rsub;
    const unsigned short* g = src + (size_t)(row0 + row) * K + k0 + colE;
    __builtin_amdgcn_global_load_lds(
        (const __attribute__((address_space(1))) void*)g,
        (__attribute__((address_space(3))) void*)(dst + c * 1024), 16, 0, 0);
  }
}

// Stage one 128x64 f32 operand tile into swizzled bf16 LDS (fallback path).
__device__ inline void stage_tile_f32(unsigned char* dst, const float* src, int row0,
                                      int rowMax, int K, int k0, int tid) {
  #pragma unroll
  for (int i = 0; i < 8; ++i) {
    int c = tid + i * 256;
    int row = c >> 4, col4 = c & 15;
    int off = (row * 128 + col4 * 8) ^ ((row & 7) << 4);
    f32x4 v = {};
    if (row0 + row < rowMax)
      v = *reinterpret_cast<const f32x4*>(src + (size_t)(row0 + row) * K + k0 + col4 * 4);
    cvt_store8(dst + off, v);
  }
}

// ---------------- GEMM (NT): C[M,N] = A[M,K] @ B[N,K]^T, MFMA bf16 ----------------
// 1D grid, XCD-chunked super-tiling (see round 7 notes).
template<int MODE, typename ATy, typename BTy>
__global__ __launch_bounds__(256) void gemm_nt(
    const ATy* __restrict__ A, const BTy* __restrict__ Bw,
    int M, int K, int mtiles, int ntiles,
    unsigned short* __restrict__ Qo, unsigned short* __restrict__ Ko,
    unsigned short* __restrict__ Vt,
    float* __restrict__ Out, const float* __restrict__ bias)
{
  const int cpx = gridDim.x >> 3;            // grid is a multiple of 8
  const int lg = (blockIdx.x & 7) * cpx + (blockIdx.x >> 3);
  const int per_sr = ntiles << 3;
  const int sr = lg / per_sr, rem = lg - sr * per_sr;
  const int nt = rem >> 3, mt = sr * 8 + (rem & 7);
  if (mt >= mtiles) return;                  // uniform whole-block exit (pre-barrier)
  const int m0 = mt * 128, n0 = nt * 128;

  __shared__ __align__(16) unsigned char As[128 * 128];
  __shared__ __align__(16) unsigned char Bs[128 * 128];
  const int tid = threadIdx.x;
  const int lane = tid & 63, w = tid >> 6;
  const int r = lane & 15, g = lane >> 4;
  const int wr = (w >> 1) * 64, wc = (w & 1) * 64;
  f32x4 acc[4][4] = {};

  for (int k0 = 0; k0 < K; k0 += 64) {
    if constexpr (sizeof(ATy) == 2) {
      stage_dma(As, (const unsigned short*)A, m0, K, k0, w, lane);
      stage_dma(Bs, (const unsigned short*)Bw, n0, K, k0, w, lane);
    } else {
      stage_tile_f32(As, (const float*)A,  m0, M,       K, k0, tid);
      stage_tile_f32(Bs, (const float*)Bw, n0, 1 << 30, K, k0, tid);
    }
    __syncthreads();

    s16x8 af[4][2], bf[4][2];
    #pragma unroll
    for (int mi = 0; mi < 4; ++mi) {
      int row = wr + mi * 16 + r;
      #pragma unroll
      for (int ks = 0; ks < 2; ++ks)
        af[mi][ks] = *reinterpret_cast<const s16x8*>(
            As + ((row * 128 + ks * 64 + g * 16) ^ ((row & 7) << 4)));
    }
    #pragma unroll
    for (int ni = 0; ni < 4; ++ni) {
      int row = wc + ni * 16 + r;
      #pragma unroll
      for (int ks = 0; ks < 2; ++ks)
        bf[ni][ks] = *reinterpret_cast<const s16x8*>(
            Bs + ((row * 128 + ks * 64 + g * 16) ^ ((row & 7) << 4)));
    }
    #pragma unroll
    for (int mi = 0; mi < 4; ++mi)
      #pragma unroll
      for (int ni = 0; ni < 4; ++ni) {
        acc[mi][ni] = __builtin_amdgcn_mfma_f32_16x16x32_bf16(
            as_bf16(af[mi][0]), as_bf16(bf[ni][0]), acc[mi][ni], 0, 0, 0);
        acc[mi][ni] = __builtin_amdgcn_mfma_f32_16x16x32_bf16(
            as_bf16(af[mi][1]), as_bf16(bf[ni][1]), acc[mi][ni], 0, 0, 0);
      }
    __syncthreads();
  }

  // ---- epilogue.  C/D layout: col = lane&15 (r), row = (lane>>4)*4 + reg ----
  #pragma unroll
  for (int mi = 0; mi < 4; ++mi) {
    #pragma unroll
    for (int ni = 0; ni < 4; ++ni) {
      int gc = n0 + wc + ni * 16 + r;
      #pragma unroll
      for (int i = 0; i < 4; ++i) {
        int gr = m0 + wr + mi * 16 + g * 4 + i;
        if (gr >= M) continue;
        float val = acc[mi][ni][i];
        if (MODE == 0) {
          int b = gr / NTOK, n = gr - b * NTOK;
          int which = gc / CDIM, rem2 = gc - which * CDIM;
          int h = rem2 >> 6, d = rem2 & 63;
          int bh = b * HEADS + h;
          unsigned short bv = f2bf(val);
          if (which == 0)      Qo[((size_t)bh * NTOK + n) * HD + d] = bv;
          else if (which == 1) Ko[((size_t)bh * NTOK + n) * HD + d] = bv;
          else                 Vt[((size_t)bh * HD + d) * NP + n] = bv;
        } else {
          Out[(size_t)gr * CDIM + gc] = val + bias[gc];   // f32 store
        }
      }
    }
  }
}

// ---------------- Flash attention: per (b,h), 64 q-rows per block (4 waves x 16) --------
// 1D grid with XCD swizzle: all 10 q-tile blocks of one head land on the SAME XCD.
__global__ __launch_bounds__(256) void attn_kernel(
    const unsigned short* __restrict__ Q, const unsigned short* __restrict__ Kd,
    const unsigned short* __restrict__ Vt, unsigned short* __restrict__ AO)
{
  const int cpx = gridDim.x >> 3;             // 1920/8 = 240
  const int lg = (blockIdx.x & 7) * cpx + (blockIdx.x >> 3);
  const int bh = lg / 10, qt = lg - bh * 10;

  __shared__ __align__(16) unsigned char Pl[4][2048];
  const int tid = threadIdx.x;
  const int w = tid >> 6, lane = tid & 63;
  const int r = lane & 15, g = lane >> 4;
  const int q0 = qt * 64 + w * 16;
  const unsigned short* Qb = Q + (size_t)bh * NTOK * HD;
  const unsigned short* Kb = Kd + (size_t)bh * NTOK * HD;
  const unsigned short* Vb = Vt + (size_t)bh * HD * NP;
  unsigned char* P = Pl[w];

  int qr = q0 + r; if (qr > NTOK - 1) qr = NTOK - 1;
  s16x8 aq0 = *reinterpret_cast<const s16x8*>(Qb + (size_t)qr * HD + g * 8);
  s16x8 aq1 = *reinterpret_cast<const s16x8*>(Qb + (size_t)qr * HD + 32 + g * 8);

  f32x4 O[4] = {};
  float m2[4], l[4];
  #pragma unroll
  for (int i = 0; i < 4; ++i) { m2[i] = -3.0e38f; l[i] = 0.f; }
  const float sl = ATT_SCALE * LOG2E;

  for (int kt = 0; kt < 10; ++kt) {
    const int kb = kt * 64;
    f32x4 s[4] = {};
    #pragma unroll
    for (int f = 0; f < 4; ++f) {
      int kk = kb + f * 16 + r; if (kk > NTOK - 1) kk = NTOK - 1;
      s16x8 b0 = *reinterpret_cast<const s16x8*>(Kb + (size_t)kk * HD + g * 8);
      s16x8 b1 = *reinterpret_cast<const s16x8*>(Kb + (size_t)kk * HD + 32 + g * 8);
      s[f] = __builtin_amdgcn_mfma_f32_16x16x32_bf16(as_bf16(aq0), as_bf16(b0), s[f], 0, 0, 0);
      s[f] = __builtin_amdgcn_mfma_f32_16x16x32_bf16(as_bf16(aq1), as_bf16(b1), s[f], 0, 0, 0);
    }
    float rmax[4];
    #pragma unroll
    for (int i = 0; i < 4; ++i) rmax[i] = -3.0e38f;
    #pragma unroll
    for (int f = 0; f < 4; ++f) {
      const bool valid = (kb + f * 16 + r) < NTOK;
      #pragma unroll
      for (int i = 0; i < 4; ++i) {
        float v = valid ? s[f][i] * sl : -3.0e38f;
        s[f][i] = v;
        rmax[i] = fmaxf(rmax[i], v);
      }
    }
    #pragma unroll
    for (int off = 1; off < 16; off <<= 1)
      #pragma unroll
      for (int i = 0; i < 4; ++i) rmax[i] = fmaxf(rmax[i], __shfl_xor(rmax[i], off, 64));

    float alpha[4], rs[4];
    #pragma unroll
    for (int i = 0; i < 4; ++i) {
      float mn = fmaxf(m2[i], rmax[i]);
      alpha[i] = exp2f(m2[i] - mn);            // m2 <= mn by construction
      m2[i] = mn;
      rs[i] = 0.f;
    }
    #pragma unroll
    for (int f = 0; f < 4; ++f) {
      #pragma unroll
      for (int i = 0; i < 4; ++i) {
        float p = exp2f(s[f][i] - m2[i]);      // s <= m2; masked keys underflow to 0
        rs[i] += p;
        int prow = g * 4 + i;
        int boff = (prow * 128 + (f * 16 + r) * 2) ^ ((prow & 7) << 4);
        *reinterpret_cast<unsigned short*>(P + boff) = hbf(p);
      }
    }
    #pragma unroll
    for (int off = 1; off < 16; off <<= 1)
      #pragma unroll
      for (int i = 0; i < 4; ++i) rs[i] += __shfl_xor(rs[i], off, 64);
    #pragma unroll
    for (int i = 0; i < 4; ++i) l[i] = l[i] * alpha[i] + rs[i];
    #pragma unroll
    for (int f = 0; f < 4; ++f)
      #pragma unroll
      for (int i = 0; i < 4; ++i) O[f][i] *= alpha[i];

    #pragma unroll
    for (int ks = 0; ks < 2; ++ks) {
      s16x8 pa = *reinterpret_cast<const s16x8*>(
          P + ((r * 128 + ks * 64 + g * 16) ^ ((r & 7) << 4)));
      int nn = kb + ks * 32 + g * 8; if (nn >= NTOK) nn = 0;   // masked keys have p=0
      #pragma unroll
      for (int f = 0; f < 4; ++f) {
        s16x8 bv = *reinterpret_cast<const s16x8*>(Vb + (size_t)(f * 16 + r) * NP + nn);
        O[f] = __builtin_amdgcn_mfma_f32_16x16x32_bf16(as_bf16(pa), as_bf16(bv), O[f], 0, 0, 0);
      }
    }
  }

  const int b = bh / HEADS, h = bh - b * HEADS;
  float inv[4];
  #pragma unroll
  for (int i = 0; i < 4; ++i) inv[i] = 1.0f / fmaxf(l[i], 1e-20f);
  #pragma unroll
  for (int f = 0; f < 4; ++f)
    #pragma unroll
    for (int i = 0; i < 4; ++i) {
      int row = q0 + g * 4 + i;
      if (row < NTOK)
        AO[((size_t)(b * NTOK + row)) * CDIM + h * HD + f * 16 + r] = hbf(O[f][i] * inv[i]);
    }
}

// ---------------- Scores phase A: per (b,h) CLS-softmax + partial v-norm^2 ------------
__global__ __launch_bounds__(256) void scores_partial(
    const unsigned short* __restrict__ Q, const unsigned short* __restrict__ Kd,
    const unsigned short* __restrict__ Vt,
    float* __restrict__ SigPart, float* __restrict__ VnPart)
{
  const int bh = blockIdx.x;
  const int tid = threadIdx.x;
  __shared__ float qv[64];
  __shared__ float red[256];
  if (tid < 64) qv[tid] = bf2f(Q[(size_t)bh * NTOK * HD + tid]);
  __syncthreads();
  const float sl = ATT_SCALE * LOG2E;
  const unsigned short* Kb = Kd + (size_t)bh * NTOK * HD;
  const unsigned short* Vb = Vt + (size_t)bh * HD * NP;

  float sv[3];
  #pragma unroll
  for (int j = 0; j < 3; ++j) {
    int k = tid + j * 256;
    float s = -3.0e38f;
    if (k < NTOK) {
      const unsigned short* kr = Kb + (size_t)k * HD;
      float acc = 0.f;
      #pragma unroll
      for (int d8 = 0; d8 < 8; ++d8) {
        s16x8 kv = *reinterpret_cast<const s16x8*>(kr + d8 * 8);
        #pragma unroll
        for (int e = 0; e < 8; ++e) acc += qv[d8 * 8 + e] * bf2f((unsigned short)kv[e]);
      }
      s = acc * sl;
    }
    sv[j] = s;
  }
  float lm = fmaxf(fmaxf(sv[0], sv[1]), sv[2]);
  red[tid] = lm; __syncthreads();
  for (int st = 128; st > 0; st >>= 1) {
    if (tid < st) red[tid] = fmaxf(red[tid], red[tid + st]);
    __syncthreads();
  }
  float mx = red[0]; __syncthreads();
  float pv[3], ps = 0.f;
  #pragma unroll
  for (int j = 0; j < 3; ++j) { pv[j] = exp2f(fminf(sv[j] - mx, 0.f)); ps += pv[j]; }
  red[tid] = ps; __syncthreads();
  for (int st = 128; st > 0; st >>= 1) {
    if (tid < st) red[tid] += red[tid + st];
    __syncthreads();
  }
  const float itot = 1.f / fmaxf(red[0], 1e-20f);
  #pragma unroll
  for (int j = 0; j < 3; ++j) {
    int k = tid + j * 256;
    if (k < NTOK) SigPart[(size_t)bh * NP + k] = pv[j] * itot;
  }
  float vacc[3] = {0.f, 0.f, 0.f};
  for (int d = 0; d < HD; ++d) {
    const unsigned short* vr = Vb + (size_t)d * NP;
    #pragma unroll
    for (int j = 0; j < 3; ++j) {
      int k = tid + j * 256;
      if (k < NTOK) { float v = bf2f(vr[k]); vacc[j] += v * v; }
    }
  }
  #pragma unroll
  for (int j = 0; j < 3; ++j) {
    int k = tid + j * 256;
    if (k < NTOK) VnPart[(size_t)bh * NP + k] = vacc[j];
  }
}

// ---------------- Scores phase B: combine heads, normalize, write f32 ------------------
__global__ __launch_bounds__(256) void scores_final(
    const float* __restrict__ SigPart, const float* __restrict__ VnPart,
    float* __restrict__ Sc)
{
  const int b = blockIdx.x;
  const int tid = threadIdx.x;
  __shared__ float red[256];
  float wv[3]; float part = 0.f;
  #pragma unroll
  for (int j = 0; j < 3; ++j) {
    int k = tid + j * 256;
    wv[j] = 0.f;
    if (k < NTOK) {
      float sig = 0.f, vn = 0.f;
      #pragma unroll
      for (int h = 0; h < HEADS; ++h) {
        sig += SigPart[((size_t)(b * HEADS + h)) * NP + k];
        vn  += VnPart [((size_t)(b * HEADS + h)) * NP + k];
      }
      wv[j] = sig * sqrtf(vn);
      if (k >= 1) part += wv[j];
    }
  }
  red[tid] = part; __syncthreads();
  for (int st = 128; st > 0; st >>= 1) {
    if (tid < st) red[tid] += red[tid + st];
    __syncthreads();
  }
  const float itot = 1.f / fmaxf(red[0], 1e-20f);
  #pragma unroll
  for (int j = 0; j < 3; ++j) {
    int k = tid + j * 256;
    if (k == 0)         Sc[(size_t)b * NTOK] = CLS_CONST;
    else if (k < NTOK)  Sc[(size_t)b * NTOK + k] = wv[j] * itot;
  }
}

extern "C" void kernel_launch(void* const* d_in, const int* in_sizes, int n_in,
                              void* d_out, int out_size, void* d_ws, size_t ws_size,
                              hipStream_t stream) {
  (void)in_sizes; (void)n_in; (void)out_size;
  const float* x      = (const float*)d_in[0];
  const float* qkv_w  = (const float*)d_in[1];
  const float* proj_w = (const float*)d_in[2];
  const float* proj_b = (const float*)d_in[3];
  float* out    = (float*)d_out;
  float* scores = out + (size_t)MROWS * CDIM;

  const size_t xN   = (size_t)MROWS * CDIM;       // 7,090,176 (also AO elems)
  const size_t qwN  = (size_t)(3 * CDIM) * CDIM;  // 1,769,472
  const size_t pwN  = (size_t)CDIM * CDIM;        //   589,824
  const size_t qN   = (size_t)NBH * NTOK * HD;    // 7,090,176
  const size_t vtN  = (size_t)NBH * HD * NP;      // 7,274,496
  const size_t need = (xN + qwN + pwN + 2 * qN + vtN) * 2;  // 61.8 MB

  if (ws_size >= need) {
    unsigned short* xb     = (unsigned short*)d_ws;
    unsigned short* qkvwb  = xb + xN;
    unsigned short* projwb = qkvwb + qwN;
    unsigned short* Q      = projwb + pwN;
    unsigned short* K      = Q + qN;
    unsigned short* Vt     = K + qN;
    unsigned short* AO     = xb;                     // x dead after QKV GEMM
    float* SigPart = (float*)qkvwb;                  // qkv_w dead after QKV GEMM
    float* VnPart  = SigPart + (size_t)NBH * NP;

    cvt3_kernel<<<2048, 256, 0, stream>>>(
        x, xb, (int)(xN / 8), qkv_w, qkvwb, (int)(qwN / 8), proj_w, projwb, (int)(pwN / 8));
    gemm_nt<0, unsigned short, unsigned short><<<1440, 256, 0, stream>>>(
        xb, qkvwb, MROWS, CDIM, 73, 18, Q, K, Vt, nullptr, nullptr);
    attn_kernel<<<1920, 256, 0, stream>>>(Q, K, Vt, AO);
    gemm_nt<1, unsigned short, unsigned short><<<480, 256, 0, stream>>>(
        AO, projwb, MROWS, CDIM, 73, 6, nullptr, nullptr, nullptr, out, proj_b);
    scores_partial<<<dim3(NBH), 256, 0, stream>>>(Q, K, Vt, SigPart, VnPart);
    scores_final<<<dim3(NB), 256, 0, stream>>>(SigPart, VnPart, scores);
  } else {
    // Fallback: proven round-7 layout (57.1 MB), f32 staging.
    unsigned short* Q  = (unsigned short*)d_ws;
    unsigned short* K  = Q + qN;
    unsigned short* Vt = K + qN;
    unsigned short* AO = Vt + vtN;
    float* SigPart = (float*)AO;                     // AO dead after proj
    float* VnPart  = SigPart + (size_t)NBH * NP;

    gemm_nt<0, float, float><<<1440, 256, 0, stream>>>(
        x, qkv_w, MROWS, CDIM, 73, 18, Q, K, Vt, nullptr, nullptr);
    attn_kernel<<<1920, 256, 0, stream>>>(Q, K, Vt, AO);
    gemm_nt<1, unsigned short, float><<<480, 256, 0, stream>>>(
        AO, proj_w, MROWS, CDIM, 73, 6, nullptr, nullptr, nullptr, out, proj_b);
    scores_partial<<<dim3(NBH), 256, 0, stream>>>(Q, K, Vt, SigPart, VnPart);
    scores_final<<<dim3(NB), 256, 0, stream>>>(SigPart, VnPart, scores);
  }
}